// Round 12
// baseline (741.738 us; speedup 1.0000x reference)
//
#include <hip/hip_runtime.h>
#include <hip/hip_bf16.h>

typedef __attribute__((ext_vector_type(4))) float f32x4;
typedef __attribute__((ext_vector_type(8))) short bf16x8;

#define VOCAB 32000
#define DIMS 1024
#define BATCH 2
#define SEQ 2048
#define ROWS (BATCH * SEQ)  // 4096
#define NC 128              // cumsum chunks per sequence
#define CL 16               // chunk length; NC*CL == SEQ

// ---------- helpers ----------
static __device__ __forceinline__ unsigned short f2bf(float f) {
  unsigned int u = __float_as_uint(f);
  unsigned int r = u + 0x7fffu + ((u >> 16) & 1u);
  return (unsigned short)(r >> 16);
}

// ---------- fp32 -> bf16 bulk convert ----------
__global__ void cvt_f32_bf16(const float* __restrict__ src,
                             unsigned short* __restrict__ dst, int n4) {
  int i = blockIdx.x * blockDim.x + threadIdx.x;
  int stride = gridDim.x * blockDim.x;
  for (; i < n4; i += stride) {
    float4 v = ((const float4*)src)[i];
    ushort4 o = {f2bf(v.x), f2bf(v.y), f2bf(v.z), f2bf(v.w)};
    ((ushort4*)dst)[i] = o;
  }
}

// ---------- embedding gather + convert ----------
__global__ void gather_emb(const int* __restrict__ idx,
                           const float* __restrict__ emb,
                           unsigned short* __restrict__ eB) {
  const int row = blockIdx.x;
  const int t = threadIdx.x;
  const int token = idx[row];
  const float4* src = (const float4*)(emb + (size_t)token * DIMS);
  float4 v = src[t];
  ushort4 o = {f2bf(v.x), f2bf(v.y), f2bf(v.z), f2bf(v.w)};
  ((ushort4*)(eB + (size_t)row * DIMS))[t] = o;
}

// ---------- old 128x128 NT GEMM (kept for the small V projection) ----------
__global__ __launch_bounds__(256) void gemm_bt(
    const unsigned short* __restrict__ A, const unsigned short* __restrict__ B,
    float* __restrict__ C, const float* __restrict__ bias, int K, int ldC) {
  __shared__ __align__(16) unsigned short sA[128 * 32];
  __shared__ __align__(16) unsigned short sB[128 * 32];

  const int tid = threadIdx.x;
  const int lane = tid & 63;
  const int w = tid >> 6;
  const int wr = w >> 1;
  const int wc = w & 1;
  const long mBase = (long)blockIdx.x * 128;
  const long nBase = (long)blockIdx.y * 128;

  const unsigned short* Ati = A + mBase * K;
  const unsigned short* Bti = B + nBase * K;

  const int srow0 = w * 32;
  const int sr = lane >> 2;
  const int ske = (lane & 3) * 8;

  f32x4 acc[4][4] = {};

  for (int kt = 0; kt < K; kt += 32) {
    __syncthreads();
#pragma unroll
    for (int i = 0; i < 2; ++i) {
      const int r = srow0 + i * 16;
      __builtin_amdgcn_global_load_lds(
          (const __attribute__((address_space(1))) unsigned int*)(
              Ati + (long)(r + sr) * K + kt + ske),
          (__attribute__((address_space(3))) unsigned int*)(&sA[r * 32]),
          16, 0, 0);
      __builtin_amdgcn_global_load_lds(
          (const __attribute__((address_space(1))) unsigned int*)(
              Bti + (long)(r + sr) * K + kt + ske),
          (__attribute__((address_space(3))) unsigned int*)(&sB[r * 32]),
          16, 0, 0);
    }
    __syncthreads();

    bf16x8 af[4], bfr[4];
#pragma unroll
    for (int mi = 0; mi < 4; ++mi)
      af[mi] = *(const bf16x8*)&sA[(wr * 64 + mi * 16 + (lane & 15)) * 32 +
                                   8 * (lane >> 4)];
#pragma unroll
    for (int ni = 0; ni < 4; ++ni)
      bfr[ni] = *(const bf16x8*)&sB[(wc * 64 + ni * 16 + (lane & 15)) * 32 +
                                    8 * (lane >> 4)];
#pragma unroll
    for (int mi = 0; mi < 4; ++mi)
#pragma unroll
      for (int ni = 0; ni < 4; ++ni)
        acc[mi][ni] = __builtin_amdgcn_mfma_f32_16x16x32_bf16(
            af[mi], bfr[ni], acc[mi][ni], 0, 0, 0);
  }

  const int rq = lane >> 4;
  const int cl = lane & 15;
#pragma unroll
  for (int ni = 0; ni < 4; ++ni) {
    const long c = nBase + wc * 64 + ni * 16 + cl;
    const float bv = bias ? bias[c] : 0.0f;
#pragma unroll
    for (int mi = 0; mi < 4; ++mi) {
      const long r = mBase + wr * 64 + mi * 16 + rq * 4;
#pragma unroll
      for (int j = 0; j < 4; ++j)
        C[(r + j) * (long)ldC + c] = acc[mi][ni][j] + bv;
    }
  }
}

// ---------- 256x128 NT GEMM, B direct-to-register (no B LDS) ----------
// ROUND 12: r4-r11 pinned at ~33% MfmaUtil across 5 schedules, 2 occupancies,
// XCD affinity, 3 tile shapes, barrier-count halving. All of them REARRANGED
// work between the LDS pipe (~790 cyc/window: 64KB frag reads + 24KB staging
// writes) and the MFMA pipe (620 cyc). This round REMOVES work: B-fragments
// load straight from global (L2-hot; B n-tile re-read by 16 m-blocks) into
// registers. NT layout makes each B-frag a k-contiguous 16B/lane dwordx4
// (uniform SGPR base + 32-bit per-lane voffset; 16 x 64B segments/instr).
//  - LDS now A-only: 16KB write + 32KB read = 48KB/window (-45%).
//  - LDS = 3 x 16KB tri-buffered A (48 KiB) -> still 2 blocks/CU, and the
//    tri-buffer keeps the r11 single-barrier window (no WAR).
//  - issue order per window: bar -> 4 B-loads -> A-stage(t+2) -> A ds_reads
//    -> compiler's counted vmcnt for B (leaves the 2 newer stage loads in
//    flight) -> 16 MFMA.
//  - ledger: entering window t only stage(t+1)(x2) outstanding; vmcnt(2) at
//    window top = steady-state no-op, retires stage(0) at t=0. B(t)'s
//    pre-MFMA wait retires stage(t+1) -> tile t+1 visible after bar(t+1).
//  - A swizzle = r4 involution (conflicts 0); B needs none.
__global__ __launch_bounds__(512, 4) void gemm_dirB(
    const unsigned short* __restrict__ A,  // [M][K] bf16, K-contiguous
    const unsigned short* __restrict__ B,  // [N][K] bf16, K-contiguous
    float* __restrict__ C,                 // [M][ldC] fp32
    const float* __restrict__ bias,        // [>=N] fp32 or nullptr
    int K, int ldC) {
  __shared__ __align__(16) unsigned short ldsA[3][256 * 32];  // 48 KiB

  const int tid = threadIdx.x;
  const int lane = tid & 63;
  const int w = tid >> 6;  // wave 0..7
  const int wr = w >> 1;   // 0..3 -> A row-quarter
  const int wc = w & 1;    // 0..1 -> B col-half
  const long mBase = (long)blockIdx.x * 256;
  const long nBase = (long)blockIdx.y * 128;
  const int NT = K >> 5;  // BK=32 windows

  const int rl = lane & 15;
  const int koffR = ((lane >> 4) * 8) ^ (((rl >> 1) & 3) << 3);
  const int skel = ((lane & 3) * 8) ^ (((lane >> 3) & 3) << 3);

  // hoisted per-lane A stage pointers (advance += 32 elems per stage)
  const unsigned short* ap0 =
      A + (mBase + 0 + w * 16 + (lane >> 2)) * (long)K + skel;
  const unsigned short* ap1 =
      A + (mBase + 128 + w * 16 + (lane >> 2)) * (long)K + skel;

  // B direct: uniform base + per-lane 32-bit byte offsets (frag layout:
  // row = nBase + wc*64 + ni*16 + rl, k-span 8 elems at (lane>>4)*8)
  const char* Bb = (const char*)(B + nBase * (long)K);
  int boff[4];
#pragma unroll
  for (int ni = 0; ni < 4; ++ni)
    boff[ni] = ((wc * 64 + ni * 16 + rl) * K + (lane >> 4) * 8) * 2;

#define GL(p, d)                                                    \
  __builtin_amdgcn_global_load_lds(                                 \
      (const __attribute__((address_space(1))) unsigned int*)(p),   \
      (__attribute__((address_space(3))) unsigned int*)(d), 16, 0, 0)
#define STAGE_A(buf)                      \
  do {                                    \
    GL(ap0, (buf) + (0 + w * 16) * 32);   \
    GL(ap1, (buf) + (128 + w * 16) * 32); \
    ap0 += 32;                            \
    ap1 += 32;                            \
  } while (0)
#define LDF(pl, r) (*(const bf16x8*)&(pl)[(r) * 32 + koffR])

  f32x4 acc[4][4] = {};

  unsigned short* aR = ldsA[0];
  unsigned short* aN = ldsA[1];
  unsigned short* aS = ldsA[2];

  // ---- prologue: stage A windows 0,1 (4 loads/wave outstanding) ----
  STAGE_A(aR);
  STAGE_A(aN);

  for (int t = 0; t < NT; ++t) {
    // retire our tile-t A-stage (steady-state no-op; t=0 retires stage(0)),
    // then join waves so all tile-t LDS writes are visible
    asm volatile("s_waitcnt vmcnt(2)" ::: "memory");
    __builtin_amdgcn_s_barrier();

    // B frags straight from L2 (issued first so the compiler's pre-MFMA
    // vmcnt leaves the newer stage loads in flight)
    bf16x8 b[4];
#pragma unroll
    for (int ni = 0; ni < 4; ++ni) {
      b[ni] = *(const bf16x8*)(Bb + boff[ni]);
      boff[ni] += 64;  // BK=32 elems
    }

    // prefetch A tile t+2 into the buffer last read in window t-1
    if (t + 2 < NT) STAGE_A(aS);

    bf16x8 a[4];
#pragma unroll
    for (int mi = 0; mi < 4; ++mi) a[mi] = LDF(aR, wr * 64 + mi * 16 + rl);

    __builtin_amdgcn_s_setprio(1);
#pragma unroll
    for (int mi = 0; mi < 4; ++mi)
#pragma unroll
      for (int ni = 0; ni < 4; ++ni)
        acc[mi][ni] = __builtin_amdgcn_mfma_f32_16x16x32_bf16(
            a[mi], b[ni], acc[mi][ni], 0, 0, 0);
    __builtin_amdgcn_s_setprio(0);

    // rotate tri-buffer: R <- N <- S <- R
    unsigned short* tmp = aR;
    aR = aN;
    aN = aS;
    aS = tmp;
  }
#undef LDF
#undef STAGE_A
#undef GL

  // ---- epilogue: C/D frag mapping col=lane&15, row=4*(lane>>4)+reg [m89] ----
  const int rq = lane >> 4;
  const int cl = lane & 15;
#pragma unroll
  for (int ni = 0; ni < 4; ++ni) {
    const long c = nBase + wc * 64 + ni * 16 + cl;
    const float bv = bias ? bias[c] : 0.0f;
#pragma unroll
    for (int mi = 0; mi < 4; ++mi) {
      const long r = mBase + wr * 64 + mi * 16 + rq * 4;
#pragma unroll
      for (int j = 0; j < 4; ++j)
        C[(r + j) * (long)ldC + c] = acc[mi][ni][j] + bv;
    }
  }
}

// ---------- causal cumulative mean (chunked scan) ----------
__global__ void chunk_sums(const float* __restrict__ V,
                           float* __restrict__ part) {
  const int bc = blockIdx.x;
  const int b = bc >> 7;
  const int c = bc & (NC - 1);
  const int d0 = threadIdx.x * 4;
  const float* vp = V + ((size_t)b * SEQ + (size_t)c * CL) * DIMS + d0;
  float4 s = {0.f, 0.f, 0.f, 0.f};
#pragma unroll
  for (int l = 0; l < CL; ++l) {
    float4 v = *(const float4*)(vp + (size_t)l * DIMS);
    s.x += v.x; s.y += v.y; s.z += v.z; s.w += v.w;
  }
  float* pp = part + ((size_t)b * DIMS + d0) * NC + c;
  pp[0 * NC] = s.x; pp[1 * NC] = s.y; pp[2 * NC] = s.z; pp[3 * NC] = s.w;
}

__global__ void chunk_scan(float* __restrict__ part) {
  const int g = blockIdx.x * blockDim.x + threadIdx.x;
  float* p = part + (size_t)g * NC;
  float run = 0.f;
#pragma unroll 4
  for (int c = 0; c < NC; ++c) {
    float t = p[c];
    p[c] = run;
    run += t;
  }
}

__global__ void cum_avg(const float* __restrict__ V,
                        const float* __restrict__ part,
                        unsigned short* __restrict__ avgB) {
  const int bc = blockIdx.x;
  const int b = bc >> 7;
  const int c = bc & (NC - 1);
  const int d0 = threadIdx.x * 4;
  const float* pp = part + ((size_t)b * DIMS + d0) * NC + c;
  float4 run = {pp[0 * NC], pp[1 * NC], pp[2 * NC], pp[3 * NC]};
  const float* vp = V + ((size_t)b * SEQ + (size_t)c * CL) * DIMS + d0;
  unsigned short* op = avgB + ((size_t)b * SEQ + (size_t)c * CL) * DIMS + d0;
#pragma unroll
  for (int l = 0; l < CL; ++l) {
    float4 v = *(const float4*)(vp + (size_t)l * DIMS);
    run.x += v.x; run.y += v.y; run.z += v.z; run.w += v.w;
    const float inv = 1.0f / (float)(c * CL + l + 1);
    ushort4 o = {f2bf(run.x * inv), f2bf(run.y * inv), f2bf(run.z * inv),
                 f2bf(run.w * inv)};
    *(ushort4*)(op + (size_t)l * DIMS) = o;
  }
}

// ---------- workspace layout (bytes, 256-aligned) ----------
#define WS_EB 0UL                   // bf16 [4096][1024]   8,388,608
#define WS_WV 8388608UL             // bf16 [1024][1024]   2,097,152
#define WS_WO 10485760UL            // bf16 [32000][1024] 65,536,000
#define WS_V 76021760UL             // f32  [4096][1024]  16,777,216
#define WS_AVG 92798976UL           // bf16 [4096][1024]   8,388,608
#define WS_PART 101187584UL         // f32  [2][1024][128] 1,048,576
#define WS_NEED 102236160UL

extern "C" void kernel_launch(void* const* d_in, const int* in_sizes, int n_in,
                              void* d_out, int out_size, void* d_ws,
                              size_t ws_size, hipStream_t stream) {
  const int* idx = (const int*)d_in[0];
  const float* emb = (const float*)d_in[1];
  const float* W_V = (const float*)d_in[2];
  const float* W_out = (const float*)d_in[3];
  const float* b_out = (const float*)d_in[4];
  float* out = (float*)d_out;

  if (ws_size < WS_NEED) return;

  char* ws = (char*)d_ws;
  unsigned short* eB = (unsigned short*)(ws + WS_EB);
  unsigned short* wvB = (unsigned short*)(ws + WS_WV);
  unsigned short* woB = (unsigned short*)(ws + WS_WO);
  float* V = (float*)(ws + WS_V);
  unsigned short* avgB = (unsigned short*)(ws + WS_AVG);
  float* part = (float*)(ws + WS_PART);

  hipLaunchKernelGGL(cvt_f32_bf16, dim3(1024), dim3(256), 0, stream, W_V, wvB,
                     (DIMS * DIMS) / 4);
  hipLaunchKernelGGL(cvt_f32_bf16, dim3(2048), dim3(256), 0, stream, W_out,
                     woB, (VOCAB * DIMS) / 4);
  hipLaunchKernelGGL(gather_emb, dim3(ROWS), dim3(256), 0, stream, idx, emb,
                     eB);
  // V = e @ W_V^T  (M=4096, N=1024, K=1024) — old 128^2 kernel, 256 blocks
  hipLaunchKernelGGL(gemm_bt, dim3(ROWS / 128, DIMS / 128), dim3(256), 0,
                     stream, eB, wvB, V, (const float*)nullptr, DIMS, DIMS);
  hipLaunchKernelGGL(chunk_sums, dim3(BATCH * NC), dim3(256), 0, stream, V,
                     part);
  hipLaunchKernelGGL(chunk_scan, dim3((BATCH * DIMS) / 256), dim3(256), 0,
                     stream, part);
  hipLaunchKernelGGL(cum_avg, dim3(BATCH * NC), dim3(256), 0, stream, V, part,
                     avgB);
  // out = avg @ W_out^T + b_out  (M=4096, N=32000, K=1024)
  // grid x = m-tiles (16, fastest): concurrent B working set small,
  // W_out streams once (round-2 counter evidence).
  hipLaunchKernelGGL(gemm_dirB, dim3(ROWS / 256, VOCAB / 128), dim3(512), 0,
                     stream, avgB, woB, out, b_out, DIMS, VOCAB);
}

// Round 13
// 486.422 us; speedup vs baseline: 1.5249x; 1.5249x over previous
//
#include <hip/hip_runtime.h>
#include <hip/hip_bf16.h>

typedef __attribute__((ext_vector_type(4))) float f32x4;
typedef __attribute__((ext_vector_type(8))) short bf16x8;

#define VOCAB 32000
#define DIMS 1024
#define BATCH 2
#define SEQ 2048
#define ROWS (BATCH * SEQ)  // 4096
#define NC 128              // cumsum chunks per sequence
#define CL 16               // chunk length; NC*CL == SEQ

// ---------- helpers ----------
static __device__ __forceinline__ unsigned short f2bf(float f) {
  unsigned int u = __float_as_uint(f);
  unsigned int r = u + 0x7fffu + ((u >> 16) & 1u);
  return (unsigned short)(r >> 16);
}

// ---------- fused fp32 -> bf16 convert for BOTH weight tensors ----------
__global__ void cvt_both(const float* __restrict__ a,
                         unsigned short* __restrict__ da, int n4a,
                         const float* __restrict__ b,
                         unsigned short* __restrict__ db, int n4b) {
  int i = blockIdx.x * blockDim.x + threadIdx.x;
  const int s = gridDim.x * blockDim.x;
  const int tot = n4a + n4b;
  for (; i < tot; i += s) {
    const float4* src;
    ushort4* dst;
    int j;
    if (i < n4a) {
      src = (const float4*)a; dst = (ushort4*)da; j = i;
    } else {
      src = (const float4*)b; dst = (ushort4*)db; j = i - n4a;
    }
    float4 v = src[j];
    ushort4 o = {f2bf(v.x), f2bf(v.y), f2bf(v.z), f2bf(v.w)};
    dst[j] = o;
  }
}

// ---------- embedding gather + convert ----------
__global__ void gather_emb(const int* __restrict__ idx,
                           const float* __restrict__ emb,
                           unsigned short* __restrict__ eB) {
  const int row = blockIdx.x;
  const int t = threadIdx.x;
  const int token = idx[row];
  const float4* src = (const float4*)(emb + (size_t)token * DIMS);
  float4 v = src[t];
  ushort4 o = {f2bf(v.x), f2bf(v.y), f2bf(v.z), f2bf(v.w)};
  ((ushort4*)(eB + (size_t)row * DIMS))[t] = o;
}

// ---------- old 128x128 NT GEMM (kept for the small V projection) ----------
__global__ __launch_bounds__(256) void gemm_bt(
    const unsigned short* __restrict__ A, const unsigned short* __restrict__ B,
    float* __restrict__ C, const float* __restrict__ bias, int K, int ldC) {
  __shared__ __align__(16) unsigned short sA[128 * 32];
  __shared__ __align__(16) unsigned short sB[128 * 32];

  const int tid = threadIdx.x;
  const int lane = tid & 63;
  const int w = tid >> 6;
  const int wr = w >> 1;
  const int wc = w & 1;
  const long mBase = (long)blockIdx.x * 128;
  const long nBase = (long)blockIdx.y * 128;

  const unsigned short* Ati = A + mBase * K;
  const unsigned short* Bti = B + nBase * K;

  const int srow0 = w * 32;
  const int sr = lane >> 2;
  const int ske = (lane & 3) * 8;

  f32x4 acc[4][4] = {};

  for (int kt = 0; kt < K; kt += 32) {
    __syncthreads();
#pragma unroll
    for (int i = 0; i < 2; ++i) {
      const int r = srow0 + i * 16;
      __builtin_amdgcn_global_load_lds(
          (const __attribute__((address_space(1))) unsigned int*)(
              Ati + (long)(r + sr) * K + kt + ske),
          (__attribute__((address_space(3))) unsigned int*)(&sA[r * 32]),
          16, 0, 0);
      __builtin_amdgcn_global_load_lds(
          (const __attribute__((address_space(1))) unsigned int*)(
              Bti + (long)(r + sr) * K + kt + ske),
          (__attribute__((address_space(3))) unsigned int*)(&sB[r * 32]),
          16, 0, 0);
    }
    __syncthreads();

    bf16x8 af[4], bfr[4];
#pragma unroll
    for (int mi = 0; mi < 4; ++mi)
      af[mi] = *(const bf16x8*)&sA[(wr * 64 + mi * 16 + (lane & 15)) * 32 +
                                   8 * (lane >> 4)];
#pragma unroll
    for (int ni = 0; ni < 4; ++ni)
      bfr[ni] = *(const bf16x8*)&sB[(wc * 64 + ni * 16 + (lane & 15)) * 32 +
                                    8 * (lane >> 4)];
#pragma unroll
    for (int mi = 0; mi < 4; ++mi)
#pragma unroll
      for (int ni = 0; ni < 4; ++ni)
        acc[mi][ni] = __builtin_amdgcn_mfma_f32_16x16x32_bf16(
            af[mi], bfr[ni], acc[mi][ni], 0, 0, 0);
  }

  const int rq = lane >> 4;
  const int cl = lane & 15;
#pragma unroll
  for (int ni = 0; ni < 4; ++ni) {
    const long c = nBase + wc * 64 + ni * 16 + cl;
    const float bv = bias ? bias[c] : 0.0f;
#pragma unroll
    for (int mi = 0; mi < 4; ++mi) {
      const long r = mBase + wr * 64 + mi * 16 + rq * 4;
#pragma unroll
      for (int j = 0; j < 4; ++j)
        C[(r + j) * (long)ldC + c] = acc[mi][ni][j] + bv;
    }
  }
}

// ---------- 256x128 BK=64 tri-buffer NT GEMM (big output projection) ----------
// ROUND 13: r12 inverted the LDS-throughput theory (removing B-LDS HURT 2x:
// global latency in-window is fatal, LDS latency is fine). Remaining residue:
// per-window RECOUPLING cost (each barrier re-phase-locks 16 waves; each
// window pays LDS-FIFO + MFMA tail + vmcnt join). This round halves the
// window count: BK=64, tri-buffered (3 x 48 KiB = 144 KiB, 1 block/CU --
// occupancy proven irrelevant in r8/r9). Single barrier per window (r11).
// Also drops setprio: m190 measured it NEGATIVE on barrier-locked GEMMs.
// Ledger (6 loads/wave/window: A 4 + B 2): prologue {0,1} = 12 out; window t
// entry: vmcnt(6) retires exactly stage(t) (leaves stage(t+1)'s 6); barrier
// makes all waves' tile-t writes visible. stage(t+2) -> buffer read at t-1
// (WAR >=1 barrier upstream). Tail t==NT-1: only own 6 out -> vmcnt(0).
// Swizzle for 128-B rows = r7 involution (conflicts measured 0):
//   read col (ks*32+qtr*8) ^ ((row&7)<<3); stage source col pre-swizzled.
__global__ __launch_bounds__(512, 1) void gemm_bk64(
    const unsigned short* __restrict__ A,  // [M][K] bf16, K-contiguous
    const unsigned short* __restrict__ B,  // [N][K] bf16, K-contiguous
    float* __restrict__ C,                 // [M][ldC] fp32
    const float* __restrict__ bias,        // [>=N] fp32 or nullptr
    int K, int ldC) {
  __shared__ __align__(16) unsigned short lds[3][384 * 64];  // 144 KiB

  const int tid = threadIdx.x;
  const int lane = tid & 63;
  const int w = tid >> 6;  // wave 0..7
  const int wr = w >> 1;   // 0..3 -> A row-quarter (64 rows)
  const int wc = w & 1;    // 0..1 -> B col-half (64 rows)
  const long mBase = (long)blockIdx.x * 256;
  const long nBase = (long)blockIdx.y * 128;
  const int NT = K >> 6;  // BK=64 windows (16 at K=1024)

  const int rl = lane & 15;
  const int qtr = lane >> 4;                  // 0..3
  const int swz = (rl & 7) << 3;              // read-side XOR, elements
  const int skel = ((lane & 7) ^ ((lane >> 3) & 7)) << 3;  // stage source col

  // hoisted per-lane global stage pointers (advance += 64 elems per window)
  const unsigned short* ap[4];
#pragma unroll
  for (int j = 0; j < 4; ++j)
    ap[j] = A + (mBase + w * 32 + j * 8 + (lane >> 3)) * (long)K + skel;
  const unsigned short* bp[2];
#pragma unroll
  for (int j = 0; j < 2; ++j)
    bp[j] = B + (nBase + w * 16 + j * 8 + (lane >> 3)) * (long)K + skel;

#define GL(p, d)                                                    \
  __builtin_amdgcn_global_load_lds(                                 \
      (const __attribute__((address_space(1))) unsigned int*)(p),   \
      (__attribute__((address_space(3))) unsigned int*)(d), 16, 0, 0)
#define STAGE_ALL(buf)                                   \
  do {                                                   \
    GL(ap[0], (buf) + (w * 32 + 0) * 64);                \
    GL(ap[1], (buf) + (w * 32 + 8) * 64);                \
    GL(ap[2], (buf) + (w * 32 + 16) * 64);               \
    GL(ap[3], (buf) + (w * 32 + 24) * 64);               \
    GL(bp[0], (buf) + 16384 + (w * 16 + 0) * 64);        \
    GL(bp[1], (buf) + 16384 + (w * 16 + 8) * 64);        \
    ap[0] += 64; ap[1] += 64; ap[2] += 64; ap[3] += 64;  \
    bp[0] += 64; bp[1] += 64;                            \
  } while (0)
#define LDF(pl, r, ks) \
  (*(const bf16x8*)&(pl)[(r) * 64 + (((ks) * 32 + qtr * 8) ^ swz)])

  f32x4 acc[4][4] = {};

  unsigned short* bufR = lds[0];
  unsigned short* bufN = lds[1];
  unsigned short* bufS = lds[2];

  // ---- prologue: stage windows 0,1 (12 loads/wave outstanding) ----
  STAGE_ALL(bufR);
  STAGE_ALL(bufN);

  for (int t = 0; t < NT; ++t) {
    if (t == NT - 1)
      asm volatile("s_waitcnt vmcnt(0)" ::: "memory");
    else
      asm volatile("s_waitcnt vmcnt(6)" ::: "memory");
    __builtin_amdgcn_s_barrier();

    // prefetch window t+2 into the buffer last read at window t-1
    if (t + 2 < NT) STAGE_ALL(bufS);

    const unsigned short* Ap = bufR;          // [256][64]
    const unsigned short* Bp = bufR + 16384;  // [128][64]
    bf16x8 a[4][2], b[4][2];
#pragma unroll
    for (int mi = 0; mi < 4; ++mi)
#pragma unroll
      for (int ks = 0; ks < 2; ++ks)
        a[mi][ks] = LDF(Ap, wr * 64 + mi * 16 + rl, ks);
#pragma unroll
    for (int ni = 0; ni < 4; ++ni)
#pragma unroll
      for (int ks = 0; ks < 2; ++ks)
        b[ni][ks] = LDF(Bp, wc * 64 + ni * 16 + rl, ks);

#pragma unroll
    for (int ks = 0; ks < 2; ++ks)
#pragma unroll
      for (int mi = 0; mi < 4; ++mi)
#pragma unroll
        for (int ni = 0; ni < 4; ++ni)
          acc[mi][ni] = __builtin_amdgcn_mfma_f32_16x16x32_bf16(
              a[mi][ks], b[ni][ks], acc[mi][ni], 0, 0, 0);

    // rotate tri-buffer: R <- N <- S <- R
    unsigned short* tmp = bufR;
    bufR = bufN;
    bufN = bufS;
    bufS = tmp;
  }
#undef LDF
#undef STAGE_ALL
#undef GL

  // ---- epilogue: C/D frag mapping col=lane&15, row=4*(lane>>4)+reg [m89] ----
  const int rq = lane >> 4;
  const int cl = lane & 15;
#pragma unroll
  for (int ni = 0; ni < 4; ++ni) {
    const long c = nBase + wc * 64 + ni * 16 + cl;
    const float bv = bias ? bias[c] : 0.0f;
#pragma unroll
    for (int mi = 0; mi < 4; ++mi) {
      const long r = mBase + wr * 64 + mi * 16 + rq * 4;
#pragma unroll
      for (int j = 0; j < 4; ++j)
        C[(r + j) * (long)ldC + c] = acc[mi][ni][j] + bv;
    }
  }
}

// ---------- causal cumulative mean (chunked scan) ----------
__global__ void chunk_sums(const float* __restrict__ V,
                           float* __restrict__ part) {
  const int bc = blockIdx.x;
  const int b = bc >> 7;
  const int c = bc & (NC - 1);
  const int d0 = threadIdx.x * 4;
  const float* vp = V + ((size_t)b * SEQ + (size_t)c * CL) * DIMS + d0;
  float4 s = {0.f, 0.f, 0.f, 0.f};
#pragma unroll
  for (int l = 0; l < CL; ++l) {
    float4 v = *(const float4*)(vp + (size_t)l * DIMS);
    s.x += v.x; s.y += v.y; s.z += v.z; s.w += v.w;
  }
  float* pp = part + ((size_t)b * DIMS + d0) * NC + c;
  pp[0 * NC] = s.x; pp[1 * NC] = s.y; pp[2 * NC] = s.z; pp[3 * NC] = s.w;
}

__global__ void chunk_scan(float* __restrict__ part) {
  const int g = blockIdx.x * blockDim.x + threadIdx.x;
  float* p = part + (size_t)g * NC;
  float run = 0.f;
#pragma unroll 4
  for (int c = 0; c < NC; ++c) {
    float t = p[c];
    p[c] = run;
    run += t;
  }
}

__global__ void cum_avg(const float* __restrict__ V,
                        const float* __restrict__ part,
                        unsigned short* __restrict__ avgB) {
  const int bc = blockIdx.x;
  const int b = bc >> 7;
  const int c = bc & (NC - 1);
  const int d0 = threadIdx.x * 4;
  const float* pp = part + ((size_t)b * DIMS + d0) * NC + c;
  float4 run = {pp[0 * NC], pp[1 * NC], pp[2 * NC], pp[3 * NC]};
  const float* vp = V + ((size_t)b * SEQ + (size_t)c * CL) * DIMS + d0;
  unsigned short* op = avgB + ((size_t)b * SEQ + (size_t)c * CL) * DIMS + d0;
#pragma unroll
  for (int l = 0; l < CL; ++l) {
    float4 v = *(const float4*)(vp + (size_t)l * DIMS);
    run.x += v.x; run.y += v.y; run.z += v.z; run.w += v.w;
    const float inv = 1.0f / (float)(c * CL + l + 1);
    ushort4 o = {f2bf(run.x * inv), f2bf(run.y * inv), f2bf(run.z * inv),
                 f2bf(run.w * inv)};
    *(ushort4*)(op + (size_t)l * DIMS) = o;
  }
}

// ---------- workspace layout (bytes, 256-aligned) ----------
#define WS_EB 0UL                   // bf16 [4096][1024]   8,388,608
#define WS_WV 8388608UL             // bf16 [1024][1024]   2,097,152
#define WS_WO 10485760UL            // bf16 [32000][1024] 65,536,000
#define WS_V 76021760UL             // f32  [4096][1024]  16,777,216
#define WS_AVG 92798976UL           // bf16 [4096][1024]   8,388,608
#define WS_PART 101187584UL         // f32  [2][1024][128] 1,048,576
#define WS_NEED 102236160UL

extern "C" void kernel_launch(void* const* d_in, const int* in_sizes, int n_in,
                              void* d_out, int out_size, void* d_ws,
                              size_t ws_size, hipStream_t stream) {
  const int* idx = (const int*)d_in[0];
  const float* emb = (const float*)d_in[1];
  const float* W_V = (const float*)d_in[2];
  const float* W_out = (const float*)d_in[3];
  const float* b_out = (const float*)d_in[4];
  float* out = (float*)d_out;

  if (ws_size < WS_NEED) return;

  char* ws = (char*)d_ws;
  unsigned short* eB = (unsigned short*)(ws + WS_EB);
  unsigned short* wvB = (unsigned short*)(ws + WS_WV);
  unsigned short* woB = (unsigned short*)(ws + WS_WO);
  float* V = (float*)(ws + WS_V);
  unsigned short* avgB = (unsigned short*)(ws + WS_AVG);
  float* part = (float*)(ws + WS_PART);

  // fused weight converts (one launch) + embedding gather
  hipLaunchKernelGGL(cvt_both, dim3(2048), dim3(256), 0, stream, W_V, wvB,
                     (DIMS * DIMS) / 4, W_out, woB, (VOCAB * DIMS) / 4);
  hipLaunchKernelGGL(gather_emb, dim3(ROWS), dim3(256), 0, stream, idx, emb,
                     eB);
  // V = e @ W_V^T  (M=4096, N=1024, K=1024) — old 128^2 kernel, 256 blocks
  hipLaunchKernelGGL(gemm_bt, dim3(ROWS / 128, DIMS / 128), dim3(256), 0,
                     stream, eB, wvB, V, (const float*)nullptr, DIMS, DIMS);
  hipLaunchKernelGGL(chunk_sums, dim3(BATCH * NC), dim3(256), 0, stream, V,
                     part);
  hipLaunchKernelGGL(chunk_scan, dim3((BATCH * DIMS) / 256), dim3(256), 0,
                     stream, part);
  hipLaunchKernelGGL(cum_avg, dim3(BATCH * NC), dim3(256), 0, stream, V, part,
                     avgB);
  // out = avg @ W_out^T + b_out  (M=4096, N=32000, K=1024)
  // grid x = m-tiles (16, fastest): concurrent B working set small,
  // W_out streams once (round-2 counter evidence).
  hipLaunchKernelGGL(gemm_bk64, dim3(ROWS / 256, VOCAB / 128), dim3(512), 0,
                     stream, avgB, woB, out, b_out, DIMS, VOCAB);
}

// Round 14
// 469.136 us; speedup vs baseline: 1.5811x; 1.0368x over previous
//
#include <hip/hip_runtime.h>
#include <hip/hip_bf16.h>

typedef __attribute__((ext_vector_type(4))) float f32x4;
typedef __attribute__((ext_vector_type(8))) short bf16x8;

#define VOCAB 32000
#define DIMS 1024
#define BATCH 2
#define SEQ 2048
#define ROWS (BATCH * SEQ)  // 4096
#define NC 128              // cumsum chunks per sequence
#define CL 16               // chunk length; NC*CL == SEQ

// ---------- helpers ----------
static __device__ __forceinline__ unsigned short f2bf(float f) {
  unsigned int u = __float_as_uint(f);
  unsigned int r = u + 0x7fffu + ((u >> 16) & 1u);
  return (unsigned short)(r >> 16);
}

// ---------- fused fp32 -> bf16 convert for BOTH weight tensors ----------
__global__ void cvt_both(const float* __restrict__ a,
                         unsigned short* __restrict__ da, int n4a,
                         const float* __restrict__ b,
                         unsigned short* __restrict__ db, int n4b) {
  int i = blockIdx.x * blockDim.x + threadIdx.x;
  const int s = gridDim.x * blockDim.x;
  const int tot = n4a + n4b;
  for (; i < tot; i += s) {
    const float4* src;
    ushort4* dst;
    int j;
    if (i < n4a) {
      src = (const float4*)a; dst = (ushort4*)da; j = i;
    } else {
      src = (const float4*)b; dst = (ushort4*)db; j = i - n4a;
    }
    float4 v = src[j];
    ushort4 o = {f2bf(v.x), f2bf(v.y), f2bf(v.z), f2bf(v.w)};
    dst[j] = o;
  }
}

// ---------- embedding gather + convert ----------
__global__ void gather_emb(const int* __restrict__ idx,
                           const float* __restrict__ emb,
                           unsigned short* __restrict__ eB) {
  const int row = blockIdx.x;
  const int t = threadIdx.x;
  const int token = idx[row];
  const float4* src = (const float4*)(emb + (size_t)token * DIMS);
  float4 v = src[t];
  ushort4 o = {f2bf(v.x), f2bf(v.y), f2bf(v.z), f2bf(v.w)};
  ((ushort4*)(eB + (size_t)row * DIMS))[t] = o;
}

// ---------- old 128x128 NT GEMM (kept for the small V projection) ----------
__global__ __launch_bounds__(256) void gemm_bt(
    const unsigned short* __restrict__ A, const unsigned short* __restrict__ B,
    float* __restrict__ C, const float* __restrict__ bias, int K, int ldC) {
  __shared__ __align__(16) unsigned short sA[128 * 32];
  __shared__ __align__(16) unsigned short sB[128 * 32];

  const int tid = threadIdx.x;
  const int lane = tid & 63;
  const int w = tid >> 6;
  const int wr = w >> 1;
  const int wc = w & 1;
  const long mBase = (long)blockIdx.x * 128;
  const long nBase = (long)blockIdx.y * 128;

  const unsigned short* Ati = A + mBase * K;
  const unsigned short* Bti = B + nBase * K;

  const int srow0 = w * 32;
  const int sr = lane >> 2;
  const int ske = (lane & 3) * 8;

  f32x4 acc[4][4] = {};

  for (int kt = 0; kt < K; kt += 32) {
    __syncthreads();
#pragma unroll
    for (int i = 0; i < 2; ++i) {
      const int r = srow0 + i * 16;
      __builtin_amdgcn_global_load_lds(
          (const __attribute__((address_space(1))) unsigned int*)(
              Ati + (long)(r + sr) * K + kt + ske),
          (__attribute__((address_space(3))) unsigned int*)(&sA[r * 32]),
          16, 0, 0);
      __builtin_amdgcn_global_load_lds(
          (const __attribute__((address_space(1))) unsigned int*)(
              Bti + (long)(r + sr) * K + kt + ske),
          (__attribute__((address_space(3))) unsigned int*)(&sB[r * 32]),
          16, 0, 0);
    }
    __syncthreads();

    bf16x8 af[4], bfr[4];
#pragma unroll
    for (int mi = 0; mi < 4; ++mi)
      af[mi] = *(const bf16x8*)&sA[(wr * 64 + mi * 16 + (lane & 15)) * 32 +
                                   8 * (lane >> 4)];
#pragma unroll
    for (int ni = 0; ni < 4; ++ni)
      bfr[ni] = *(const bf16x8*)&sB[(wc * 64 + ni * 16 + (lane & 15)) * 32 +
                                    8 * (lane >> 4)];
#pragma unroll
    for (int mi = 0; mi < 4; ++mi)
#pragma unroll
      for (int ni = 0; ni < 4; ++ni)
        acc[mi][ni] = __builtin_amdgcn_mfma_f32_16x16x32_bf16(
            af[mi], bfr[ni], acc[mi][ni], 0, 0, 0);
  }

  const int rq = lane >> 4;
  const int cl = lane & 15;
#pragma unroll
  for (int ni = 0; ni < 4; ++ni) {
    const long c = nBase + wc * 64 + ni * 16 + cl;
    const float bv = bias ? bias[c] : 0.0f;
#pragma unroll
    for (int mi = 0; mi < 4; ++mi) {
      const long r = mBase + wr * 64 + mi * 16 + rq * 4;
#pragma unroll
      for (int j = 0; j < 4; ++j)
        C[(r + j) * (long)ldC + c] = acc[mi][ni][j] + bv;
    }
  }
}

// ---------- 256x128 NT GEMM, 128x64 wave-tiles, 4 waves, 2 blocks/CU --------
// ROUND 14: plateau analysis. Falsified: over-fetch(r2), conflicts(r4),
// alternation(r5-7), occupancy(r8-9), L3 BW(r9), VALU(r10), sync count(r11),
// LDS throughput(r12 inverted), window count(r13). Invariant never varied
// while plateaued: wave-tile 64x64 at 2 blocks/CU. LDS frag-read volume is
// FLOP/byte = WM*WN/(WM+WN): 64x64 -> 32 (8.4 GB ds_read chip-wide,
// ~344-517k cyc/CU vs 258k MFMA floor). 128x64 -> 42.7 (-25% LDS bytes);
// r10 tried it confounded (1 blk/CU, BM=512). This round: the untried cell
// = 128x64 wave-tile AND 2 blocks/CU, via 256-thread blocks (4 waves, 2mx2n).
//   BM=256 BN=128 BK=32; tri-buffer 3x24 KiB = 72 KiB (x2 blocks = 144<=160);
//   acc 128 + frags ~50 -> ~200 VGPR -> 2 waves/SIMD x 2 blocks = 8 waves/CU.
//   Single-barrier window + ledger = r11 verbatim; 4-wave sync joins (skew/2).
// Ledger (6 loads/wave/window: A 4 + B 2): prologue {0,1}=12 out; window t:
// vmcnt(6) retires stage(t) (leaves stage(t+1)'s 6); barrier -> visible.
// stage(t+2) -> buffer read at t-1 (WAR >=1 barrier upstream). Tail t==NT-1:
// only own 6 outstanding -> vmcnt(0). Swizzle = r4 involution (conflicts 0).
__global__ __launch_bounds__(256, 2) void gemm_wt128(
    const unsigned short* __restrict__ A,  // [M][K] bf16, K-contiguous
    const unsigned short* __restrict__ B,  // [N][K] bf16, K-contiguous
    float* __restrict__ C,                 // [M][ldC] fp32
    const float* __restrict__ bias,        // [>=N] fp32 or nullptr
    int K, int ldC) {
  __shared__ __align__(16) unsigned short lds[3][384 * 32];  // 72 KiB

  const int tid = threadIdx.x;
  const int lane = tid & 63;
  const int w = tid >> 6;  // wave 0..3
  const int wr = w >> 1;   // 0..1 -> A row-half (128 rows)
  const int wc = w & 1;    // 0..1 -> B col-half (64 cols)
  const long mBase = (long)blockIdx.x * 256;
  const long nBase = (long)blockIdx.y * 128;
  const int NT = K >> 5;  // BK=32 windows

  const int rl = lane & 15;
  const int koffR = ((lane >> 4) * 8) ^ (((rl >> 1) & 3) << 3);
  const int skel = ((lane & 3) * 8) ^ (((lane >> 3) & 3) << 3);

  // hoisted per-lane global stage pointers (advance += 32 elems per window)
  // wave w: A rows [w*64, w*64+64) via 4 gloads of 16 rows; B rows [w*32,+32)
  const unsigned short* ap[4];
#pragma unroll
  for (int j = 0; j < 4; ++j)
    ap[j] = A + (mBase + w * 64 + j * 16 + (lane >> 2)) * (long)K + skel;
  const unsigned short* bp[2];
#pragma unroll
  for (int j = 0; j < 2; ++j)
    bp[j] = B + (nBase + w * 32 + j * 16 + (lane >> 2)) * (long)K + skel;

#define GL(p, d)                                                    \
  __builtin_amdgcn_global_load_lds(                                 \
      (const __attribute__((address_space(1))) unsigned int*)(p),   \
      (__attribute__((address_space(3))) unsigned int*)(d), 16, 0, 0)
#define STAGE_ALL(buf)                                  \
  do {                                                  \
    GL(ap[0], (buf) + (w * 64 + 0) * 32);               \
    GL(ap[1], (buf) + (w * 64 + 16) * 32);              \
    GL(ap[2], (buf) + (w * 64 + 32) * 32);              \
    GL(ap[3], (buf) + (w * 64 + 48) * 32);              \
    GL(bp[0], (buf) + 8192 + (w * 32 + 0) * 32);        \
    GL(bp[1], (buf) + 8192 + (w * 32 + 16) * 32);       \
    ap[0] += 32; ap[1] += 32; ap[2] += 32; ap[3] += 32; \
    bp[0] += 32; bp[1] += 32;                           \
  } while (0)
#define LDF(pl, r) (*(const bf16x8*)&(pl)[(r) * 32 + koffR])

  f32x4 acc[8][4] = {};

  unsigned short* bufR = lds[0];
  unsigned short* bufN = lds[1];
  unsigned short* bufS = lds[2];

  // ---- prologue: stage windows 0,1 (12 loads/wave outstanding) ----
  STAGE_ALL(bufR);
  STAGE_ALL(bufN);

  for (int t = 0; t < NT; ++t) {
    if (t == NT - 1)
      asm volatile("s_waitcnt vmcnt(0)" ::: "memory");
    else
      asm volatile("s_waitcnt vmcnt(6)" ::: "memory");
    __builtin_amdgcn_s_barrier();

    // prefetch window t+2 into the buffer last read at window t-1
    if (t + 2 < NT) STAGE_ALL(bufS);

    const unsigned short* Ap = bufR;         // [256][32]
    const unsigned short* Bp = bufR + 8192;  // [128][32]
    bf16x8 a[8], b[4];
#pragma unroll
    for (int mi = 0; mi < 8; ++mi) a[mi] = LDF(Ap, wr * 128 + mi * 16 + rl);
#pragma unroll
    for (int ni = 0; ni < 4; ++ni) b[ni] = LDF(Bp, wc * 64 + ni * 16 + rl);

#pragma unroll
    for (int mi = 0; mi < 8; ++mi)
#pragma unroll
      for (int ni = 0; ni < 4; ++ni)
        acc[mi][ni] = __builtin_amdgcn_mfma_f32_16x16x32_bf16(
            a[mi], b[ni], acc[mi][ni], 0, 0, 0);

    // rotate tri-buffer: R <- N <- S <- R
    unsigned short* tmp = bufR;
    bufR = bufN;
    bufN = bufS;
    bufS = tmp;
  }
#undef LDF
#undef STAGE_ALL
#undef GL

  // ---- epilogue: C/D frag mapping col=lane&15, row=4*(lane>>4)+reg [m89] ----
  const int rq = lane >> 4;
  const int cl = lane & 15;
#pragma unroll
  for (int ni = 0; ni < 4; ++ni) {
    const long c = nBase + wc * 64 + ni * 16 + cl;
    const float bv = bias ? bias[c] : 0.0f;
#pragma unroll
    for (int mi = 0; mi < 8; ++mi) {
      const long r = mBase + wr * 128 + mi * 16 + rq * 4;
#pragma unroll
      for (int j = 0; j < 4; ++j)
        C[(r + j) * (long)ldC + c] = acc[mi][ni][j] + bv;
    }
  }
}

// ---------- causal cumulative mean (chunked scan) ----------
__global__ void chunk_sums(const float* __restrict__ V,
                           float* __restrict__ part) {
  const int bc = blockIdx.x;
  const int b = bc >> 7;
  const int c = bc & (NC - 1);
  const int d0 = threadIdx.x * 4;
  const float* vp = V + ((size_t)b * SEQ + (size_t)c * CL) * DIMS + d0;
  float4 s = {0.f, 0.f, 0.f, 0.f};
#pragma unroll
  for (int l = 0; l < CL; ++l) {
    float4 v = *(const float4*)(vp + (size_t)l * DIMS);
    s.x += v.x; s.y += v.y; s.z += v.z; s.w += v.w;
  }
  float* pp = part + ((size_t)b * DIMS + d0) * NC + c;
  pp[0 * NC] = s.x; pp[1 * NC] = s.y; pp[2 * NC] = s.z; pp[3 * NC] = s.w;
}

__global__ void chunk_scan(float* __restrict__ part) {
  const int g = blockIdx.x * blockDim.x + threadIdx.x;
  float* p = part + (size_t)g * NC;
  float run = 0.f;
#pragma unroll 4
  for (int c = 0; c < NC; ++c) {
    float t = p[c];
    p[c] = run;
    run += t;
  }
}

__global__ void cum_avg(const float* __restrict__ V,
                        const float* __restrict__ part,
                        unsigned short* __restrict__ avgB) {
  const int bc = blockIdx.x;
  const int b = bc >> 7;
  const int c = bc & (NC - 1);
  const int d0 = threadIdx.x * 4;
  const float* pp = part + ((size_t)b * DIMS + d0) * NC + c;
  float4 run = {pp[0 * NC], pp[1 * NC], pp[2 * NC], pp[3 * NC]};
  const float* vp = V + ((size_t)b * SEQ + (size_t)c * CL) * DIMS + d0;
  unsigned short* op = avgB + ((size_t)b * SEQ + (size_t)c * CL) * DIMS + d0;
#pragma unroll
  for (int l = 0; l < CL; ++l) {
    float4 v = *(const float4*)(vp + (size_t)l * DIMS);
    run.x += v.x; run.y += v.y; run.z += v.z; run.w += v.w;
    const float inv = 1.0f / (float)(c * CL + l + 1);
    ushort4 o = {f2bf(run.x * inv), f2bf(run.y * inv), f2bf(run.z * inv),
                 f2bf(run.w * inv)};
    *(ushort4*)(op + (size_t)l * DIMS) = o;
  }
}

// ---------- workspace layout (bytes, 256-aligned) ----------
#define WS_EB 0UL                   // bf16 [4096][1024]   8,388,608
#define WS_WV 8388608UL             // bf16 [1024][1024]   2,097,152
#define WS_WO 10485760UL            // bf16 [32000][1024] 65,536,000
#define WS_V 76021760UL             // f32  [4096][1024]  16,777,216
#define WS_AVG 92798976UL           // bf16 [4096][1024]   8,388,608
#define WS_PART 101187584UL         // f32  [2][1024][128] 1,048,576
#define WS_NEED 102236160UL

extern "C" void kernel_launch(void* const* d_in, const int* in_sizes, int n_in,
                              void* d_out, int out_size, void* d_ws,
                              size_t ws_size, hipStream_t stream) {
  const int* idx = (const int*)d_in[0];
  const float* emb = (const float*)d_in[1];
  const float* W_V = (const float*)d_in[2];
  const float* W_out = (const float*)d_in[3];
  const float* b_out = (const float*)d_in[4];
  float* out = (float*)d_out;

  if (ws_size < WS_NEED) return;

  char* ws = (char*)d_ws;
  unsigned short* eB = (unsigned short*)(ws + WS_EB);
  unsigned short* wvB = (unsigned short*)(ws + WS_WV);
  unsigned short* woB = (unsigned short*)(ws + WS_WO);
  float* V = (float*)(ws + WS_V);
  unsigned short* avgB = (unsigned short*)(ws + WS_AVG);
  float* part = (float*)(ws + WS_PART);

  // fused weight converts (one launch) + embedding gather
  hipLaunchKernelGGL(cvt_both, dim3(2048), dim3(256), 0, stream, W_V, wvB,
                     (DIMS * DIMS) / 4, W_out, woB, (VOCAB * DIMS) / 4);
  hipLaunchKernelGGL(gather_emb, dim3(ROWS), dim3(256), 0, stream, idx, emb,
                     eB);
  // V = e @ W_V^T  (M=4096, N=1024, K=1024) — old 128^2 kernel, 256 blocks
  hipLaunchKernelGGL(gemm_bt, dim3(ROWS / 128, DIMS / 128), dim3(256), 0,
                     stream, eB, wvB, V, (const float*)nullptr, DIMS, DIMS);
  hipLaunchKernelGGL(chunk_sums, dim3(BATCH * NC), dim3(256), 0, stream, V,
                     part);
  hipLaunchKernelGGL(chunk_scan, dim3((BATCH * DIMS) / 256), dim3(256), 0,
                     stream, part);
  hipLaunchKernelGGL(cum_avg, dim3(BATCH * NC), dim3(256), 0, stream, V, part,
                     avgB);
  // out = avg @ W_out^T + b_out  (M=4096, N=32000, K=1024)
  // grid x = m-tiles (16, fastest): concurrent B working set small,
  // W_out streams once (round-2 counter evidence).
  hipLaunchKernelGGL(gemm_wt128, dim3(ROWS / 256, VOCAB / 128), dim3(256), 0,
                     stream, avgB, woB, out, b_out, DIMS, VOCAB);
}

// Round 15
// 461.521 us; speedup vs baseline: 1.6072x; 1.0165x over previous
//
#include <hip/hip_runtime.h>
#include <hip/hip_bf16.h>

typedef __attribute__((ext_vector_type(4))) float f32x4;
typedef __attribute__((ext_vector_type(8))) short bf16x8;

#define VOCAB 32000
#define DIMS 1024
#define BATCH 2
#define SEQ 2048
#define ROWS (BATCH * SEQ)  // 4096
#define NC 128              // cumsum chunks per sequence
#define CL 16               // chunk length; NC*CL == SEQ

// ---------- helpers ----------
static __device__ __forceinline__ unsigned short f2bf(float f) {
  unsigned int u = __float_as_uint(f);
  unsigned int r = u + 0x7fffu + ((u >> 16) & 1u);
  return (unsigned short)(r >> 16);
}

// ---------- fused fp32 -> bf16 convert for BOTH weight tensors ----------
__global__ void cvt_both(const float* __restrict__ a,
                         unsigned short* __restrict__ da, int n4a,
                         const float* __restrict__ b,
                         unsigned short* __restrict__ db, int n4b) {
  int i = blockIdx.x * blockDim.x + threadIdx.x;
  const int s = gridDim.x * blockDim.x;
  const int tot = n4a + n4b;
  for (; i < tot; i += s) {
    const float4* src;
    ushort4* dst;
    int j;
    if (i < n4a) {
      src = (const float4*)a; dst = (ushort4*)da; j = i;
    } else {
      src = (const float4*)b; dst = (ushort4*)db; j = i - n4a;
    }
    float4 v = src[j];
    ushort4 o = {f2bf(v.x), f2bf(v.y), f2bf(v.z), f2bf(v.w)};
    dst[j] = o;
  }
}

// ---------- embedding gather + convert ----------
__global__ void gather_emb(const int* __restrict__ idx,
                           const float* __restrict__ emb,
                           unsigned short* __restrict__ eB) {
  const int row = blockIdx.x;
  const int t = threadIdx.x;
  const int token = idx[row];
  const float4* src = (const float4*)(emb + (size_t)token * DIMS);
  float4 v = src[t];
  ushort4 o = {f2bf(v.x), f2bf(v.y), f2bf(v.z), f2bf(v.w)};
  ((ushort4*)(eB + (size_t)row * DIMS))[t] = o;
}

// ---------- old 128x128 NT GEMM (kept for the small V projection) ----------
__global__ __launch_bounds__(256) void gemm_bt(
    const unsigned short* __restrict__ A, const unsigned short* __restrict__ B,
    float* __restrict__ C, const float* __restrict__ bias, int K, int ldC) {
  __shared__ __align__(16) unsigned short sA[128 * 32];
  __shared__ __align__(16) unsigned short sB[128 * 32];

  const int tid = threadIdx.x;
  const int lane = tid & 63;
  const int w = tid >> 6;
  const int wr = w >> 1;
  const int wc = w & 1;
  const long mBase = (long)blockIdx.x * 128;
  const long nBase = (long)blockIdx.y * 128;

  const unsigned short* Ati = A + mBase * K;
  const unsigned short* Bti = B + nBase * K;

  const int srow0 = w * 32;
  const int sr = lane >> 2;
  const int ske = (lane & 3) * 8;

  f32x4 acc[4][4] = {};

  for (int kt = 0; kt < K; kt += 32) {
    __syncthreads();
#pragma unroll
    for (int i = 0; i < 2; ++i) {
      const int r = srow0 + i * 16;
      __builtin_amdgcn_global_load_lds(
          (const __attribute__((address_space(1))) unsigned int*)(
              Ati + (long)(r + sr) * K + kt + ske),
          (__attribute__((address_space(3))) unsigned int*)(&sA[r * 32]),
          16, 0, 0);
      __builtin_amdgcn_global_load_lds(
          (const __attribute__((address_space(1))) unsigned int*)(
              Bti + (long)(r + sr) * K + kt + ske),
          (__attribute__((address_space(3))) unsigned int*)(&sB[r * 32]),
          16, 0, 0);
    }
    __syncthreads();

    bf16x8 af[4], bfr[4];
#pragma unroll
    for (int mi = 0; mi < 4; ++mi)
      af[mi] = *(const bf16x8*)&sA[(wr * 64 + mi * 16 + (lane & 15)) * 32 +
                                   8 * (lane >> 4)];
#pragma unroll
    for (int ni = 0; ni < 4; ++ni)
      bfr[ni] = *(const bf16x8*)&sB[(wc * 64 + ni * 16 + (lane & 15)) * 32 +
                                    8 * (lane >> 4)];
#pragma unroll
    for (int mi = 0; mi < 4; ++mi)
#pragma unroll
      for (int ni = 0; ni < 4; ++ni)
        acc[mi][ni] = __builtin_amdgcn_mfma_f32_16x16x32_bf16(
            af[mi], bfr[ni], acc[mi][ni], 0, 0, 0);
  }

  const int rq = lane >> 4;
  const int cl = lane & 15;
#pragma unroll
  for (int ni = 0; ni < 4; ++ni) {
    const long c = nBase + wc * 64 + ni * 16 + cl;
    const float bv = bias ? bias[c] : 0.0f;
#pragma unroll
    for (int mi = 0; mi < 4; ++mi) {
      const long r = mBase + wr * 64 + mi * 16 + rq * 4;
#pragma unroll
      for (int j = 0; j < 4; ++j)
        C[(r + j) * (long)ldC + c] = acc[mi][ni][j] + bv;
    }
  }
}

// ---------- 256x128 tri-buffer NT GEMM + wave-staggered read issue ----------
// ROUND 15: the zero-overlap diagnosis. r11 per window-slot: wall 3330 cyc
// = LDS service 2100 + MFMA 1242, an exact SUM. Mechanism: the barrier
// releases all 16 waves at once; every wave issues its read burst in the
// same instant; the LDS unit services them ROUND-ROBIN, so no wave's batch
// completes early -> all lgkmcnts clear ~t=2100 -> all MFMAs tail serially.
// All 12 prior variants preserved "reads co-issue" -> all equivalent.
// Fix: stagger read-burst issue by wave id (s_sleep (w&3) x ~64cyc after
// the barrier). Wave 0's batch is serviced without contention -> its MFMA
// overlaps waves 1-3's service -> pipeline instead of convoy. Sleep cost
// is absorbed by the shortened queue the slept waves see.
// Everything else = r11 verbatim (best: 347us): tri-buffer 3x24 KiB,
// single barrier/window, vmcnt(6)/tail-vmcnt(0) ledger, r4 swizzle
// (conflicts measured 0), hoisted stage pointers, 2 blocks/CU.
__global__ __launch_bounds__(512, 4) void gemm256x128_tri(
    const unsigned short* __restrict__ A,  // [M][K] bf16, K-contiguous
    const unsigned short* __restrict__ B,  // [N][K] bf16, K-contiguous
    float* __restrict__ C,                 // [M][ldC] fp32
    const float* __restrict__ bias,        // [>=N] fp32 or nullptr
    int K, int ldC) {
  __shared__ __align__(16) unsigned short lds[3][384 * 32];  // 72 KiB

  const int tid = threadIdx.x;
  const int lane = tid & 63;
  const int w = tid >> 6;  // wave 0..7
  const int wr = w >> 1;   // 0..3 -> A row-quarter
  const int wc = w & 1;    // 0..1 -> B col-half
  const long mBase = (long)blockIdx.x * 256;
  const long nBase = (long)blockIdx.y * 128;
  const int NT = K >> 5;  // BK=32 windows

  const int rl = lane & 15;
  const int koffR = ((lane >> 4) * 8) ^ (((rl >> 1) & 3) << 3);
  const int skel = ((lane & 3) * 8) ^ (((lane >> 3) & 3) << 3);

  // hoisted per-lane global source pointers (advance += 32 elems per stage)
  const unsigned short* ap0 =
      A + (mBase + 0 + w * 16 + (lane >> 2)) * (long)K + skel;
  const unsigned short* ap1 =
      A + (mBase + 128 + w * 16 + (lane >> 2)) * (long)K + skel;
  const unsigned short* bp =
      B + (nBase + w * 16 + (lane >> 2)) * (long)K + skel;

#define GL(p, d)                                                    \
  __builtin_amdgcn_global_load_lds(                                 \
      (const __attribute__((address_space(1))) unsigned int*)(p),   \
      (__attribute__((address_space(3))) unsigned int*)(d), 16, 0, 0)
#define STAGE_ALL(buf)                    \
  do {                                    \
    GL(ap0, (buf) + (0 + w * 16) * 32);   \
    GL(ap1, (buf) + (128 + w * 16) * 32); \
    GL(bp, (buf) + 8192 + w * 512);       \
    ap0 += 32; ap1 += 32; bp += 32;       \
  } while (0)
#define LDF(pl, r) (*(const bf16x8*)&(pl)[(r) * 32 + koffR])

  f32x4 acc[4][4] = {};

  // rotating buffer pointers (read / next / stage-target)
  unsigned short* bufR = lds[0];
  unsigned short* bufN = lds[1];
  unsigned short* bufS = lds[2];

  // ---- prologue: stage windows 0,1 (6 loads/wave outstanding) ----
  STAGE_ALL(bufR);
  STAGE_ALL(bufN);

  for (int t = 0; t < NT; ++t) {
    if (t == NT - 1)
      asm volatile("s_waitcnt vmcnt(0)" ::: "memory");
    else
      asm volatile("s_waitcnt vmcnt(3)" ::: "memory");
    __builtin_amdgcn_s_barrier();

    // stage t+2 first (async vmem, independent of the sleep stagger)
    if (t + 2 < NT) STAGE_ALL(bufS);

    // wave-id stagger: offset read-burst issue by ~64 cyc per (w&3) step so
    // the LDS unit services wave batches in sequence, letting early waves'
    // MFMAs overlap late waves' reads (breaks the round-robin convoy).
    if (w & 1) __builtin_amdgcn_s_sleep(1);
    if (w & 2) __builtin_amdgcn_s_sleep(2);

    const unsigned short* Ap = bufR;         // [256][32]
    const unsigned short* Bp = bufR + 8192;  // [128][32]
    bf16x8 a[4], b[4];
#pragma unroll
    for (int mi = 0; mi < 4; ++mi) a[mi] = LDF(Ap, wr * 64 + mi * 16 + rl);
#pragma unroll
    for (int ni = 0; ni < 4; ++ni) b[ni] = LDF(Bp, wc * 64 + ni * 16 + rl);

    __builtin_amdgcn_s_setprio(1);
#pragma unroll
    for (int mi = 0; mi < 4; ++mi)
#pragma unroll
      for (int ni = 0; ni < 4; ++ni)
        acc[mi][ni] = __builtin_amdgcn_mfma_f32_16x16x32_bf16(
            a[mi], b[ni], acc[mi][ni], 0, 0, 0);
    __builtin_amdgcn_s_setprio(0);

    // rotate: R <- N <- S <- R
    unsigned short* tmp = bufR;
    bufR = bufN;
    bufN = bufS;
    bufS = tmp;
  }
#undef LDF
#undef STAGE_ALL
#undef GL

  // ---- epilogue: C/D frag mapping col=lane&15, row=4*(lane>>4)+reg [m89] ----
  const int rq = lane >> 4;
  const int cl = lane & 15;
#pragma unroll
  for (int ni = 0; ni < 4; ++ni) {
    const long c = nBase + wc * 64 + ni * 16 + cl;
    const float bv = bias ? bias[c] : 0.0f;
#pragma unroll
    for (int mi = 0; mi < 4; ++mi) {
      const long r = mBase + wr * 64 + mi * 16 + rq * 4;
#pragma unroll
      for (int j = 0; j < 4; ++j)
        C[(r + j) * (long)ldC + c] = acc[mi][ni][j] + bv;
    }
  }
}

// ---------- causal cumulative mean (chunked scan) ----------
__global__ void chunk_sums(const float* __restrict__ V,
                           float* __restrict__ part) {
  const int bc = blockIdx.x;
  const int b = bc >> 7;
  const int c = bc & (NC - 1);
  const int d0 = threadIdx.x * 4;
  const float* vp = V + ((size_t)b * SEQ + (size_t)c * CL) * DIMS + d0;
  float4 s = {0.f, 0.f, 0.f, 0.f};
#pragma unroll
  for (int l = 0; l < CL; ++l) {
    float4 v = *(const float4*)(vp + (size_t)l * DIMS);
    s.x += v.x; s.y += v.y; s.z += v.z; s.w += v.w;
  }
  float* pp = part + ((size_t)b * DIMS + d0) * NC + c;
  pp[0 * NC] = s.x; pp[1 * NC] = s.y; pp[2 * NC] = s.z; pp[3 * NC] = s.w;
}

__global__ void chunk_scan(float* __restrict__ part) {
  const int g = blockIdx.x * blockDim.x + threadIdx.x;
  float* p = part + (size_t)g * NC;
  float run = 0.f;
#pragma unroll 4
  for (int c = 0; c < NC; ++c) {
    float t = p[c];
    p[c] = run;
    run += t;
  }
}

__global__ void cum_avg(const float* __restrict__ V,
                        const float* __restrict__ part,
                        unsigned short* __restrict__ avgB) {
  const int bc = blockIdx.x;
  const int b = bc >> 7;
  const int c = bc & (NC - 1);
  const int d0 = threadIdx.x * 4;
  const float* pp = part + ((size_t)b * DIMS + d0) * NC + c;
  float4 run = {pp[0 * NC], pp[1 * NC], pp[2 * NC], pp[3 * NC]};
  const float* vp = V + ((size_t)b * SEQ + (size_t)c * CL) * DIMS + d0;
  unsigned short* op = avgB + ((size_t)b * SEQ + (size_t)c * CL) * DIMS + d0;
#pragma unroll
  for (int l = 0; l < CL; ++l) {
    float4 v = *(const float4*)(vp + (size_t)l * DIMS);
    run.x += v.x; run.y += v.y; run.z += v.z; run.w += v.w;
    const float inv = 1.0f / (float)(c * CL + l + 1);
    ushort4 o = {f2bf(run.x * inv), f2bf(run.y * inv), f2bf(run.z * inv),
                 f2bf(run.w * inv)};
    *(ushort4*)(op + (size_t)l * DIMS) = o;
  }
}

// ---------- workspace layout (bytes, 256-aligned) ----------
#define WS_EB 0UL                   // bf16 [4096][1024]   8,388,608
#define WS_WV 8388608UL             // bf16 [1024][1024]   2,097,152
#define WS_WO 10485760UL            // bf16 [32000][1024] 65,536,000
#define WS_V 76021760UL             // f32  [4096][1024]  16,777,216
#define WS_AVG 92798976UL           // bf16 [4096][1024]   8,388,608
#define WS_PART 101187584UL         // f32  [2][1024][128] 1,048,576
#define WS_NEED 102236160UL

extern "C" void kernel_launch(void* const* d_in, const int* in_sizes, int n_in,
                              void* d_out, int out_size, void* d_ws,
                              size_t ws_size, hipStream_t stream) {
  const int* idx = (const int*)d_in[0];
  const float* emb = (const float*)d_in[1];
  const float* W_V = (const float*)d_in[2];
  const float* W_out = (const float*)d_in[3];
  const float* b_out = (const float*)d_in[4];
  float* out = (float*)d_out;

  if (ws_size < WS_NEED) return;

  char* ws = (char*)d_ws;
  unsigned short* eB = (unsigned short*)(ws + WS_EB);
  unsigned short* wvB = (unsigned short*)(ws + WS_WV);
  unsigned short* woB = (unsigned short*)(ws + WS_WO);
  float* V = (float*)(ws + WS_V);
  unsigned short* avgB = (unsigned short*)(ws + WS_AVG);
  float* part = (float*)(ws + WS_PART);

  // fused weight converts (one launch) + embedding gather
  hipLaunchKernelGGL(cvt_both, dim3(2048), dim3(256), 0, stream, W_V, wvB,
                     (DIMS * DIMS) / 4, W_out, woB, (VOCAB * DIMS) / 4);
  hipLaunchKernelGGL(gather_emb, dim3(ROWS), dim3(256), 0, stream, idx, emb,
                     eB);
  // V = e @ W_V^T  (M=4096, N=1024, K=1024) — old 128^2 kernel, 256 blocks
  hipLaunchKernelGGL(gemm_bt, dim3(ROWS / 128, DIMS / 128), dim3(256), 0,
                     stream, eB, wvB, V, (const float*)nullptr, DIMS, DIMS);
  hipLaunchKernelGGL(chunk_sums, dim3(BATCH * NC), dim3(256), 0, stream, V,
                     part);
  hipLaunchKernelGGL(chunk_scan, dim3((BATCH * DIMS) / 256), dim3(256), 0,
                     stream, part);
  hipLaunchKernelGGL(cum_avg, dim3(BATCH * NC), dim3(256), 0, stream, V, part,
                     avgB);
  // out = avg @ W_out^T + b_out  (M=4096, N=32000, K=1024)
  // grid x = m-tiles (16, fastest): concurrent B working set small,
  // W_out streams once (round-2 counter evidence).
  hipLaunchKernelGGL(gemm256x128_tri, dim3(ROWS / 256, VOCAB / 128), dim3(512),
                     0, stream, avgB, woB, out, b_out, DIMS, VOCAB);
}

// Round 16
// 443.700 us; speedup vs baseline: 1.6717x; 1.0402x over previous
//
#include <hip/hip_runtime.h>
#include <hip/hip_bf16.h>

typedef __attribute__((ext_vector_type(4))) float f32x4;
typedef __attribute__((ext_vector_type(16))) float f32x16;
typedef __attribute__((ext_vector_type(8))) short bf16x8;

#define VOCAB 32000
#define DIMS 1024
#define BATCH 2
#define SEQ 2048
#define ROWS (BATCH * SEQ)  // 4096
#define NC 128              // cumsum chunks per sequence
#define CL 16               // chunk length; NC*CL == SEQ

// ---------- helpers ----------
static __device__ __forceinline__ unsigned short f2bf(float f) {
  unsigned int u = __float_as_uint(f);
  unsigned int r = u + 0x7fffu + ((u >> 16) & 1u);
  return (unsigned short)(r >> 16);
}

// ---------- fused fp32 -> bf16 convert for BOTH weight tensors ----------
__global__ void cvt_both(const float* __restrict__ a,
                         unsigned short* __restrict__ da, int n4a,
                         const float* __restrict__ b,
                         unsigned short* __restrict__ db, int n4b) {
  int i = blockIdx.x * blockDim.x + threadIdx.x;
  const int s = gridDim.x * blockDim.x;
  const int tot = n4a + n4b;
  for (; i < tot; i += s) {
    const float4* src;
    ushort4* dst;
    int j;
    if (i < n4a) {
      src = (const float4*)a; dst = (ushort4*)da; j = i;
    } else {
      src = (const float4*)b; dst = (ushort4*)db; j = i - n4a;
    }
    float4 v = src[j];
    ushort4 o = {f2bf(v.x), f2bf(v.y), f2bf(v.z), f2bf(v.w)};
    dst[j] = o;
  }
}

// ---------- embedding gather + convert ----------
__global__ void gather_emb(const int* __restrict__ idx,
                           const float* __restrict__ emb,
                           unsigned short* __restrict__ eB) {
  const int row = blockIdx.x;
  const int t = threadIdx.x;
  const int token = idx[row];
  const float4* src = (const float4*)(emb + (size_t)token * DIMS);
  float4 v = src[t];
  ushort4 o = {f2bf(v.x), f2bf(v.y), f2bf(v.z), f2bf(v.w)};
  ((ushort4*)(eB + (size_t)row * DIMS))[t] = o;
}

// ---------- old 128x128 NT GEMM (kept for the small V projection) ----------
__global__ __launch_bounds__(256) void gemm_bt(
    const unsigned short* __restrict__ A, const unsigned short* __restrict__ B,
    float* __restrict__ C, const float* __restrict__ bias, int K, int ldC) {
  __shared__ __align__(16) unsigned short sA[128 * 32];
  __shared__ __align__(16) unsigned short sB[128 * 32];

  const int tid = threadIdx.x;
  const int lane = tid & 63;
  const int w = tid >> 6;
  const int wr = w >> 1;
  const int wc = w & 1;
  const long mBase = (long)blockIdx.x * 128;
  const long nBase = (long)blockIdx.y * 128;

  const unsigned short* Ati = A + mBase * K;
  const unsigned short* Bti = B + nBase * K;

  const int srow0 = w * 32;
  const int sr = lane >> 2;
  const int ske = (lane & 3) * 8;

  f32x4 acc[4][4] = {};

  for (int kt = 0; kt < K; kt += 32) {
    __syncthreads();
#pragma unroll
    for (int i = 0; i < 2; ++i) {
      const int r = srow0 + i * 16;
      __builtin_amdgcn_global_load_lds(
          (const __attribute__((address_space(1))) unsigned int*)(
              Ati + (long)(r + sr) * K + kt + ske),
          (__attribute__((address_space(3))) unsigned int*)(&sA[r * 32]),
          16, 0, 0);
      __builtin_amdgcn_global_load_lds(
          (const __attribute__((address_space(1))) unsigned int*)(
              Bti + (long)(r + sr) * K + kt + ske),
          (__attribute__((address_space(3))) unsigned int*)(&sB[r * 32]),
          16, 0, 0);
    }
    __syncthreads();

    bf16x8 af[4], bfr[4];
#pragma unroll
    for (int mi = 0; mi < 4; ++mi)
      af[mi] = *(const bf16x8*)&sA[(wr * 64 + mi * 16 + (lane & 15)) * 32 +
                                   8 * (lane >> 4)];
#pragma unroll
    for (int ni = 0; ni < 4; ++ni)
      bfr[ni] = *(const bf16x8*)&sB[(wc * 64 + ni * 16 + (lane & 15)) * 32 +
                                    8 * (lane >> 4)];
#pragma unroll
    for (int mi = 0; mi < 4; ++mi)
#pragma unroll
      for (int ni = 0; ni < 4; ++ni)
        acc[mi][ni] = __builtin_amdgcn_mfma_f32_16x16x32_bf16(
            af[mi], bfr[ni], acc[mi][ni], 0, 0, 0);
  }

  const int rq = lane >> 4;
  const int cl = lane & 15;
#pragma unroll
  for (int ni = 0; ni < 4; ++ni) {
    const long c = nBase + wc * 64 + ni * 16 + cl;
    const float bv = bias ? bias[c] : 0.0f;
#pragma unroll
    for (int mi = 0; mi < 4; ++mi) {
      const long r = mBase + wr * 64 + mi * 16 + rq * 4;
#pragma unroll
      for (int j = 0; j < 4; ++j)
        C[(r + j) * (long)ldC + c] = acc[mi][ni][j] + bv;
    }
  }
}

// ---------- 256x128 tri-buffer NT GEMM with 32x32x16 MFMA ----------
// ROUND 16: 13 nulls -> the per-window wall is a latency/issue floor, not a
// throughput queue. Last removable pipe-time: MFMA shape. 32x32x16 runs at
// 2382 TF vs 16x16x32's 2075 (m119: 2.46e-4 vs 2.96e-4 cyc/FLOP, -17%
// matrix-pipe time) and HALVES instruction count (8 vs 16 MFMA/window) at
// IDENTICAL LDS read count (8 b128/wave/window; frag bytes set by the 64x64
// wave-tile, not the MFMA shape). Single-variable swap into the r11 kernel.
//  - A/B frag (32x32x16): lane -> row lane&31, k-offset (lane>>5)*8 (analog
//    of the validated 16x16 mapping; wrong layout would fail absmax loudly).
//  - C/D: col=lane&31, row=(reg&3)+8*(reg>>2)+4*(lane>>5)  [m74/m101 HW-ver]
//  - swizzle: read block = (ks*2 + (lane>>5)) ^ ((row>>1)&3); bank walk for
//    8-lane issue groups over 32-row frags -> all 8 bank-quads distinct,
//    conflict-free. Stage side unchanged (16-row group offsets keep
//    (row>>1)&3 invariant).
// Everything else = r11 verbatim (best: 347us): tri-buffer 3x24 KiB, single
// barrier/window, vmcnt(3)/tail-vmcnt(0) ledger, hoisted stage pointers,
// 2 blocks/CU.
__global__ __launch_bounds__(512, 4) void gemm256x128_m32(
    const unsigned short* __restrict__ A,  // [M][K] bf16, K-contiguous
    const unsigned short* __restrict__ B,  // [N][K] bf16, K-contiguous
    float* __restrict__ C,                 // [M][ldC] fp32
    const float* __restrict__ bias,        // [>=N] fp32 or nullptr
    int K, int ldC) {
  __shared__ __align__(16) unsigned short lds[3][384 * 32];  // 72 KiB

  const int tid = threadIdx.x;
  const int lane = tid & 63;
  const int w = tid >> 6;  // wave 0..7
  const int wr = w >> 1;   // 0..3 -> A row-quarter (64 rows)
  const int wc = w & 1;    // 0..1 -> B col-half (64 cols)
  const long mBase = (long)blockIdx.x * 256;
  const long nBase = (long)blockIdx.y * 128;
  const int NT = K >> 5;  // BK=32 windows

  const int rl32 = lane & 31;   // frag row within 32
  const int khalf = lane >> 5;  // 0..1 -> k-offset half
  const int skel = ((lane & 3) * 8) ^ (((lane >> 3) & 3) << 3);

  // hoisted per-lane global source pointers (advance += 32 elems per stage)
  const unsigned short* ap0 =
      A + (mBase + 0 + w * 16 + (lane >> 2)) * (long)K + skel;
  const unsigned short* ap1 =
      A + (mBase + 128 + w * 16 + (lane >> 2)) * (long)K + skel;
  const unsigned short* bp =
      B + (nBase + w * 16 + (lane >> 2)) * (long)K + skel;

#define GL(p, d)                                                    \
  __builtin_amdgcn_global_load_lds(                                 \
      (const __attribute__((address_space(1))) unsigned int*)(p),   \
      (__attribute__((address_space(3))) unsigned int*)(d), 16, 0, 0)
#define STAGE_ALL(buf)                    \
  do {                                    \
    GL(ap0, (buf) + (0 + w * 16) * 32);   \
    GL(ap1, (buf) + (128 + w * 16) * 32); \
    GL(bp, (buf) + 8192 + w * 512);       \
    ap0 += 32; ap1 += 32; bp += 32;       \
  } while (0)
// read global k-block (ks*2+khalf) of row: stored at blk ^ ((row>>1)&3)
#define LDF32(pl, rowe, ks)                                             \
  (*(const bf16x8*)&(pl)[(rowe) * 32 +                                  \
                         (((((ks) * 2 + khalf) * 8)) ^                  \
                          ((((rowe) >> 1) & 3) << 3))])

  f32x16 acc[2][2] = {};

  // rotating buffer pointers (read / next / stage-target)
  unsigned short* bufR = lds[0];
  unsigned short* bufN = lds[1];
  unsigned short* bufS = lds[2];

  // ---- prologue: stage windows 0,1 (6 loads/wave outstanding) ----
  STAGE_ALL(bufR);
  STAGE_ALL(bufN);

  for (int t = 0; t < NT; ++t) {
    if (t == NT - 1)
      asm volatile("s_waitcnt vmcnt(0)" ::: "memory");
    else
      asm volatile("s_waitcnt vmcnt(3)" ::: "memory");
    __builtin_amdgcn_s_barrier();

    // stage t+2 into the buffer last read at window t-1 (WAR-safe)
    if (t + 2 < NT) STAGE_ALL(bufS);

    const unsigned short* Ap = bufR;         // [256][32]
    const unsigned short* Bp = bufR + 8192;  // [128][32]
    bf16x8 a[2][2], b[2][2];
#pragma unroll
    for (int ti = 0; ti < 2; ++ti)
#pragma unroll
      for (int ks = 0; ks < 2; ++ks)
        a[ti][ks] = LDF32(Ap, wr * 64 + ti * 32 + rl32, ks);
#pragma unroll
    for (int tj = 0; tj < 2; ++tj)
#pragma unroll
      for (int ks = 0; ks < 2; ++ks)
        b[tj][ks] = LDF32(Bp, wc * 64 + tj * 32 + rl32, ks);

    __builtin_amdgcn_s_setprio(1);
#pragma unroll
    for (int ks = 0; ks < 2; ++ks)
#pragma unroll
      for (int ti = 0; ti < 2; ++ti)
#pragma unroll
        for (int tj = 0; tj < 2; ++tj)
          acc[ti][tj] = __builtin_amdgcn_mfma_f32_32x32x16_bf16(
              a[ti][ks], b[tj][ks], acc[ti][tj], 0, 0, 0);
    __builtin_amdgcn_s_setprio(0);

    // rotate: R <- N <- S <- R
    unsigned short* tmp = bufR;
    bufR = bufN;
    bufN = bufS;
    bufS = tmp;
  }
#undef LDF32
#undef STAGE_ALL
#undef GL

  // ---- epilogue: 32x32 C/D mapping col=lane&31,
  //      row=(reg&3)+8*(reg>>2)+4*(lane>>5)   [m74/m101 HW-verified] ----
#pragma unroll
  for (int tj = 0; tj < 2; ++tj) {
    const long c = nBase + wc * 64 + tj * 32 + rl32;
    const float bv = bias ? bias[c] : 0.0f;
#pragma unroll
    for (int ti = 0; ti < 2; ++ti) {
      const long r0 = mBase + wr * 64 + ti * 32 + 4 * khalf;
#pragma unroll
      for (int reg = 0; reg < 16; ++reg) {
        const long r = r0 + (reg & 3) + 8 * (reg >> 2);
        C[r * (long)ldC + c] = acc[ti][tj][reg] + bv;
      }
    }
  }
}

// ---------- causal cumulative mean (chunked scan) ----------
__global__ void chunk_sums(const float* __restrict__ V,
                           float* __restrict__ part) {
  const int bc = blockIdx.x;
  const int b = bc >> 7;
  const int c = bc & (NC - 1);
  const int d0 = threadIdx.x * 4;
  const float* vp = V + ((size_t)b * SEQ + (size_t)c * CL) * DIMS + d0;
  float4 s = {0.f, 0.f, 0.f, 0.f};
#pragma unroll
  for (int l = 0; l < CL; ++l) {
    float4 v = *(const float4*)(vp + (size_t)l * DIMS);
    s.x += v.x; s.y += v.y; s.z += v.z; s.w += v.w;
  }
  float* pp = part + ((size_t)b * DIMS + d0) * NC + c;
  pp[0 * NC] = s.x; pp[1 * NC] = s.y; pp[2 * NC] = s.z; pp[3 * NC] = s.w;
}

__global__ void chunk_scan(float* __restrict__ part) {
  const int g = blockIdx.x * blockDim.x + threadIdx.x;
  float* p = part + (size_t)g * NC;
  float run = 0.f;
#pragma unroll 4
  for (int c = 0; c < NC; ++c) {
    float t = p[c];
    p[c] = run;
    run += t;
  }
}

__global__ void cum_avg(const float* __restrict__ V,
                        const float* __restrict__ part,
                        unsigned short* __restrict__ avgB) {
  const int bc = blockIdx.x;
  const int b = bc >> 7;
  const int c = bc & (NC - 1);
  const int d0 = threadIdx.x * 4;
  const float* pp = part + ((size_t)b * DIMS + d0) * NC + c;
  float4 run = {pp[0 * NC], pp[1 * NC], pp[2 * NC], pp[3 * NC]};
  const float* vp = V + ((size_t)b * SEQ + (size_t)c * CL) * DIMS + d0;
  unsigned short* op = avgB + ((size_t)b * SEQ + (size_t)c * CL) * DIMS + d0;
#pragma unroll
  for (int l = 0; l < CL; ++l) {
    float4 v = *(const float4*)(vp + (size_t)l * DIMS);
    run.x += v.x; run.y += v.y; run.z += v.z; run.w += v.w;
    const float inv = 1.0f / (float)(c * CL + l + 1);
    ushort4 o = {f2bf(run.x * inv), f2bf(run.y * inv), f2bf(run.z * inv),
                 f2bf(run.w * inv)};
    *(ushort4*)(op + (size_t)l * DIMS) = o;
  }
}

// ---------- workspace layout (bytes, 256-aligned) ----------
#define WS_EB 0UL                   // bf16 [4096][1024]   8,388,608
#define WS_WV 8388608UL             // bf16 [1024][1024]   2,097,152
#define WS_WO 10485760UL            // bf16 [32000][1024] 65,536,000
#define WS_V 76021760UL             // f32  [4096][1024]  16,777,216
#define WS_AVG 92798976UL           // bf16 [4096][1024]   8,388,608
#define WS_PART 101187584UL         // f32  [2][1024][128] 1,048,576
#define WS_NEED 102236160UL

extern "C" void kernel_launch(void* const* d_in, const int* in_sizes, int n_in,
                              void* d_out, int out_size, void* d_ws,
                              size_t ws_size, hipStream_t stream) {
  const int* idx = (const int*)d_in[0];
  const float* emb = (const float*)d_in[1];
  const float* W_V = (const float*)d_in[2];
  const float* W_out = (const float*)d_in[3];
  const float* b_out = (const float*)d_in[4];
  float* out = (float*)d_out;

  if (ws_size < WS_NEED) return;

  char* ws = (char*)d_ws;
  unsigned short* eB = (unsigned short*)(ws + WS_EB);
  unsigned short* wvB = (unsigned short*)(ws + WS_WV);
  unsigned short* woB = (unsigned short*)(ws + WS_WO);
  float* V = (float*)(ws + WS_V);
  unsigned short* avgB = (unsigned short*)(ws + WS_AVG);
  float* part = (float*)(ws + WS_PART);

  // fused weight converts (one launch) + embedding gather
  hipLaunchKernelGGL(cvt_both, dim3(2048), dim3(256), 0, stream, W_V, wvB,
                     (DIMS * DIMS) / 4, W_out, woB, (VOCAB * DIMS) / 4);
  hipLaunchKernelGGL(gather_emb, dim3(ROWS), dim3(256), 0, stream, idx, emb,
                     eB);
  // V = e @ W_V^T  (M=4096, N=1024, K=1024) — old 128^2 kernel, 256 blocks
  hipLaunchKernelGGL(gemm_bt, dim3(ROWS / 128, DIMS / 128), dim3(256), 0,
                     stream, eB, wvB, V, (const float*)nullptr, DIMS, DIMS);
  hipLaunchKernelGGL(chunk_sums, dim3(BATCH * NC), dim3(256), 0, stream, V,
                     part);
  hipLaunchKernelGGL(chunk_scan, dim3((BATCH * DIMS) / 256), dim3(256), 0,
                     stream, part);
  hipLaunchKernelGGL(cum_avg, dim3(BATCH * NC), dim3(256), 0, stream, V, part,
                     avgB);
  // out = avg @ W_out^T + b_out  (M=4096, N=32000, K=1024)
  // grid x = m-tiles (16, fastest): concurrent B working set small,
  // W_out streams once (round-2 counter evidence).
  hipLaunchKernelGGL(gemm256x128_m32, dim3(ROWS / 256, VOCAB / 128), dim3(512),
                     0, stream, avgB, woB, out, b_out, DIMS, VOCAB);
}

// Round 17
// 441.367 us; speedup vs baseline: 1.6805x; 1.0053x over previous
//
#include <hip/hip_runtime.h>
#include <hip/hip_bf16.h>

typedef __attribute__((ext_vector_type(4))) float f32x4;
typedef __attribute__((ext_vector_type(16))) float f32x16;
typedef __attribute__((ext_vector_type(8))) short bf16x8;

#define VOCAB 32000
#define DIMS 1024
#define BATCH 2
#define SEQ 2048
#define ROWS (BATCH * SEQ)  // 4096
#define NC 128              // cumsum chunks per sequence
#define CL 16               // chunk length; NC*CL == SEQ

// ---------- helpers ----------
static __device__ __forceinline__ unsigned short f2bf(float f) {
  unsigned int u = __float_as_uint(f);
  unsigned int r = u + 0x7fffu + ((u >> 16) & 1u);
  return (unsigned short)(r >> 16);
}

// ---------- fused fp32 -> bf16 convert for BOTH weight tensors ----------
__global__ void cvt_both(const float* __restrict__ a,
                         unsigned short* __restrict__ da, int n4a,
                         const float* __restrict__ b,
                         unsigned short* __restrict__ db, int n4b) {
  int i = blockIdx.x * blockDim.x + threadIdx.x;
  const int s = gridDim.x * blockDim.x;
  const int tot = n4a + n4b;
  for (; i < tot; i += s) {
    const float4* src;
    ushort4* dst;
    int j;
    if (i < n4a) {
      src = (const float4*)a; dst = (ushort4*)da; j = i;
    } else {
      src = (const float4*)b; dst = (ushort4*)db; j = i - n4a;
    }
    float4 v = src[j];
    ushort4 o = {f2bf(v.x), f2bf(v.y), f2bf(v.z), f2bf(v.w)};
    dst[j] = o;
  }
}

// ---------- embedding gather + convert ----------
__global__ void gather_emb(const int* __restrict__ idx,
                           const float* __restrict__ emb,
                           unsigned short* __restrict__ eB) {
  const int row = blockIdx.x;
  const int t = threadIdx.x;
  const int token = idx[row];
  const float4* src = (const float4*)(emb + (size_t)token * DIMS);
  float4 v = src[t];
  ushort4 o = {f2bf(v.x), f2bf(v.y), f2bf(v.z), f2bf(v.w)};
  ((ushort4*)(eB + (size_t)row * DIMS))[t] = o;
}

// ---------- old 128x128 NT GEMM (kept for the small V projection) ----------
__global__ __launch_bounds__(256) void gemm_bt(
    const unsigned short* __restrict__ A, const unsigned short* __restrict__ B,
    float* __restrict__ C, const float* __restrict__ bias, int K, int ldC) {
  __shared__ __align__(16) unsigned short sA[128 * 32];
  __shared__ __align__(16) unsigned short sB[128 * 32];

  const int tid = threadIdx.x;
  const int lane = tid & 63;
  const int w = tid >> 6;
  const int wr = w >> 1;
  const int wc = w & 1;
  const long mBase = (long)blockIdx.x * 128;
  const long nBase = (long)blockIdx.y * 128;

  const unsigned short* Ati = A + mBase * K;
  const unsigned short* Bti = B + nBase * K;

  const int srow0 = w * 32;
  const int sr = lane >> 2;
  const int ske = (lane & 3) * 8;

  f32x4 acc[4][4] = {};

  for (int kt = 0; kt < K; kt += 32) {
    __syncthreads();
#pragma unroll
    for (int i = 0; i < 2; ++i) {
      const int r = srow0 + i * 16;
      __builtin_amdgcn_global_load_lds(
          (const __attribute__((address_space(1))) unsigned int*)(
              Ati + (long)(r + sr) * K + kt + ske),
          (__attribute__((address_space(3))) unsigned int*)(&sA[r * 32]),
          16, 0, 0);
      __builtin_amdgcn_global_load_lds(
          (const __attribute__((address_space(1))) unsigned int*)(
              Bti + (long)(r + sr) * K + kt + ske),
          (__attribute__((address_space(3))) unsigned int*)(&sB[r * 32]),
          16, 0, 0);
    }
    __syncthreads();

    bf16x8 af[4], bfr[4];
#pragma unroll
    for (int mi = 0; mi < 4; ++mi)
      af[mi] = *(const bf16x8*)&sA[(wr * 64 + mi * 16 + (lane & 15)) * 32 +
                                   8 * (lane >> 4)];
#pragma unroll
    for (int ni = 0; ni < 4; ++ni)
      bfr[ni] = *(const bf16x8*)&sB[(wc * 64 + ni * 16 + (lane & 15)) * 32 +
                                    8 * (lane >> 4)];
#pragma unroll
    for (int mi = 0; mi < 4; ++mi)
#pragma unroll
      for (int ni = 0; ni < 4; ++ni)
        acc[mi][ni] = __builtin_amdgcn_mfma_f32_16x16x32_bf16(
            af[mi], bfr[ni], acc[mi][ni], 0, 0, 0);
  }

  const int rq = lane >> 4;
  const int cl = lane & 15;
#pragma unroll
  for (int ni = 0; ni < 4; ++ni) {
    const long c = nBase + wc * 64 + ni * 16 + cl;
    const float bv = bias ? bias[c] : 0.0f;
#pragma unroll
    for (int mi = 0; mi < 4; ++mi) {
      const long r = mBase + wr * 64 + mi * 16 + rq * 4;
#pragma unroll
      for (int j = 0; j < 4; ++j)
        C[(r + j) * (long)ldC + c] = acc[mi][ni][j] + bv;
    }
  }
}

// ---------- 256x128 tri-buffer NT GEMM, 32x32x16 MFMA, fixed swizzle -------
// ROUND 17: r16's 32x32 swap WON (347->334, MfmaUtil 33->36.7) but
// introduced SQ_LDS_BANK_CONFLICT = 3.28e7 = exactly 4 extra cyc x 8.19e6
// b128 reads. Diagnosis: r16's frag read has k-block constant over lanes
// 0-31, and slot(row) has period 16 -> lanes 16 apart alias to the same
// bank-quad (r4's conflict-free pattern varied blk with lane>>4, which is
// why it measured 0). Fix: extend the involution with the row's bit 4:
//   s(r) = ((r>>1)&3) ^ (((r>>4)&1)<<1)
// -> rows 16 apart differ by XOR 2 in block index -> distinct quads.
// Verified by hand: 8-lane groups cover 8 distinct quads; (i,i+16) pairs
// differ; (i,i+16,i+32,i+48) quads give blk' = {b, b^2, b^1, b^3}.
// Read side: row mod 32 == lane&31 always -> swizzle is a pure per-lane
// constant. Stage side: staged rows are w*16+(l>>2) (+128) -> (row>>4)&1
// = w&1 -> one per-wave XOR term. Both-sides involution preserved;
// global coalescing unchanged (permutation within 64B spans).
// Everything else = r16 verbatim (tri-buffer 3x24 KiB, single barrier,
// vmcnt(3)/tail-vmcnt(0) ledger, hoisted stage pointers, 2 blocks/CU).
__global__ __launch_bounds__(512, 4) void gemm256x128_m32(
    const unsigned short* __restrict__ A,  // [M][K] bf16, K-contiguous
    const unsigned short* __restrict__ B,  // [N][K] bf16, K-contiguous
    float* __restrict__ C,                 // [M][ldC] fp32
    const float* __restrict__ bias,        // [>=N] fp32 or nullptr
    int K, int ldC) {
  __shared__ __align__(16) unsigned short lds[3][384 * 32];  // 72 KiB

  const int tid = threadIdx.x;
  const int lane = tid & 63;
  const int w = tid >> 6;  // wave 0..7
  const int wr = w >> 1;   // 0..3 -> A row-quarter (64 rows)
  const int wc = w & 1;    // 0..1 -> B col-half (64 cols)
  const long mBase = (long)blockIdx.x * 256;
  const long nBase = (long)blockIdx.y * 128;
  const int NT = K >> 5;  // BK=32 windows

  const int rl32 = lane & 31;   // frag row within 32
  const int khalf = lane >> 5;  // 0..1 -> k-offset half
  // read-side swizzle: s = ((row>>1)&3) ^ (((row>>4)&1)<<1); row==rl32 mod 32
  // and (row>>4)&1 == (lane>>4)&1 for all frag rows (bases are mult. of 32).
  const int swR = ((((rl32 >> 1) & 3) ^ (((lane >> 4) & 1) << 1)) << 3);
  // stage-side: staged row = {0,128} + w*16 + (lane>>2) -> (row>>4)&1 = w&1
  const int skel =
      (((lane & 3) ^ ((lane >> 3) & 3) ^ ((w & 1) << 1)) << 3);

  // hoisted per-lane global source pointers (advance += 32 elems per stage)
  const unsigned short* ap0 =
      A + (mBase + 0 + w * 16 + (lane >> 2)) * (long)K + skel;
  const unsigned short* ap1 =
      A + (mBase + 128 + w * 16 + (lane >> 2)) * (long)K + skel;
  const unsigned short* bp =
      B + (nBase + w * 16 + (lane >> 2)) * (long)K + skel;

#define GL(p, d)                                                    \
  __builtin_amdgcn_global_load_lds(                                 \
      (const __attribute__((address_space(1))) unsigned int*)(p),   \
      (__attribute__((address_space(3))) unsigned int*)(d), 16, 0, 0)
#define STAGE_ALL(buf)                    \
  do {                                    \
    GL(ap0, (buf) + (0 + w * 16) * 32);   \
    GL(ap1, (buf) + (128 + w * 16) * 32); \
    GL(bp, (buf) + 8192 + w * 512);       \
    ap0 += 32; ap1 += 32; bp += 32;       \
  } while (0)
// read global k-block (ks*2+khalf) of row: stored at blk ^ s(row) -> swR
#define LDF32(pl, rowe, ks) \
  (*(const bf16x8*)&(pl)[(rowe) * 32 + ((((ks) * 2 + khalf) * 8) ^ swR)])

  f32x16 acc[2][2] = {};

  // rotating buffer pointers (read / next / stage-target)
  unsigned short* bufR = lds[0];
  unsigned short* bufN = lds[1];
  unsigned short* bufS = lds[2];

  // ---- prologue: stage windows 0,1 (6 loads/wave outstanding) ----
  STAGE_ALL(bufR);
  STAGE_ALL(bufN);

  for (int t = 0; t < NT; ++t) {
    if (t == NT - 1)
      asm volatile("s_waitcnt vmcnt(0)" ::: "memory");
    else
      asm volatile("s_waitcnt vmcnt(3)" ::: "memory");
    __builtin_amdgcn_s_barrier();

    // stage t+2 into the buffer last read at window t-1 (WAR-safe)
    if (t + 2 < NT) STAGE_ALL(bufS);

    const unsigned short* Ap = bufR;         // [256][32]
    const unsigned short* Bp = bufR + 8192;  // [128][32]
    bf16x8 a[2][2], b[2][2];
#pragma unroll
    for (int ti = 0; ti < 2; ++ti)
#pragma unroll
      for (int ks = 0; ks < 2; ++ks)
        a[ti][ks] = LDF32(Ap, wr * 64 + ti * 32 + rl32, ks);
#pragma unroll
    for (int tj = 0; tj < 2; ++tj)
#pragma unroll
      for (int ks = 0; ks < 2; ++ks)
        b[tj][ks] = LDF32(Bp, wc * 64 + tj * 32 + rl32, ks);

    __builtin_amdgcn_s_setprio(1);
#pragma unroll
    for (int ks = 0; ks < 2; ++ks)
#pragma unroll
      for (int ti = 0; ti < 2; ++ti)
#pragma unroll
        for (int tj = 0; tj < 2; ++tj)
          acc[ti][tj] = __builtin_amdgcn_mfma_f32_32x32x16_bf16(
              a[ti][ks], b[tj][ks], acc[ti][tj], 0, 0, 0);
    __builtin_amdgcn_s_setprio(0);

    // rotate: R <- N <- S <- R
    unsigned short* tmp = bufR;
    bufR = bufN;
    bufN = bufS;
    bufS = tmp;
  }
#undef LDF32
#undef STAGE_ALL
#undef GL

  // ---- epilogue: 32x32 C/D mapping col=lane&31,
  //      row=(reg&3)+8*(reg>>2)+4*(lane>>5)   [m74/m101 HW-verified] ----
#pragma unroll
  for (int tj = 0; tj < 2; ++tj) {
    const long c = nBase + wc * 64 + tj * 32 + rl32;
    const float bv = bias ? bias[c] : 0.0f;
#pragma unroll
    for (int ti = 0; ti < 2; ++ti) {
      const long r0 = mBase + wr * 64 + ti * 32 + 4 * khalf;
#pragma unroll
      for (int reg = 0; reg < 16; ++reg) {
        const long r = r0 + (reg & 3) + 8 * (reg >> 2);
        C[r * (long)ldC + c] = acc[ti][tj][reg] + bv;
      }
    }
  }
}

// ---------- causal cumulative mean (chunked scan) ----------
__global__ void chunk_sums(const float* __restrict__ V,
                           float* __restrict__ part) {
  const int bc = blockIdx.x;
  const int b = bc >> 7;
  const int c = bc & (NC - 1);
  const int d0 = threadIdx.x * 4;
  const float* vp = V + ((size_t)b * SEQ + (size_t)c * CL) * DIMS + d0;
  float4 s = {0.f, 0.f, 0.f, 0.f};
#pragma unroll
  for (int l = 0; l < CL; ++l) {
    float4 v = *(const float4*)(vp + (size_t)l * DIMS);
    s.x += v.x; s.y += v.y; s.z += v.z; s.w += v.w;
  }
  float* pp = part + ((size_t)b * DIMS + d0) * NC + c;
  pp[0 * NC] = s.x; pp[1 * NC] = s.y; pp[2 * NC] = s.z; pp[3 * NC] = s.w;
}

__global__ void chunk_scan(float* __restrict__ part) {
  const int g = blockIdx.x * blockDim.x + threadIdx.x;
  float* p = part + (size_t)g * NC;
  float run = 0.f;
#pragma unroll 4
  for (int c = 0; c < NC; ++c) {
    float t = p[c];
    p[c] = run;
    run += t;
  }
}

__global__ void cum_avg(const float* __restrict__ V,
                        const float* __restrict__ part,
                        unsigned short* __restrict__ avgB) {
  const int bc = blockIdx.x;
  const int b = bc >> 7;
  const int c = bc & (NC - 1);
  const int d0 = threadIdx.x * 4;
  const float* pp = part + ((size_t)b * DIMS + d0) * NC + c;
  float4 run = {pp[0 * NC], pp[1 * NC], pp[2 * NC], pp[3 * NC]};
  const float* vp = V + ((size_t)b * SEQ + (size_t)c * CL) * DIMS + d0;
  unsigned short* op = avgB + ((size_t)b * SEQ + (size_t)c * CL) * DIMS + d0;
#pragma unroll
  for (int l = 0; l < CL; ++l) {
    float4 v = *(const float4*)(vp + (size_t)l * DIMS);
    run.x += v.x; run.y += v.y; run.z += v.z; run.w += v.w;
    const float inv = 1.0f / (float)(c * CL + l + 1);
    ushort4 o = {f2bf(run.x * inv), f2bf(run.y * inv), f2bf(run.z * inv),
                 f2bf(run.w * inv)};
    *(ushort4*)(op + (size_t)l * DIMS) = o;
  }
}

// ---------- workspace layout (bytes, 256-aligned) ----------
#define WS_EB 0UL                   // bf16 [4096][1024]   8,388,608
#define WS_WV 8388608UL             // bf16 [1024][1024]   2,097,152
#define WS_WO 10485760UL            // bf16 [32000][1024] 65,536,000
#define WS_V 76021760UL             // f32  [4096][1024]  16,777,216
#define WS_AVG 92798976UL           // bf16 [4096][1024]   8,388,608
#define WS_PART 101187584UL         // f32  [2][1024][128] 1,048,576
#define WS_NEED 102236160UL

extern "C" void kernel_launch(void* const* d_in, const int* in_sizes, int n_in,
                              void* d_out, int out_size, void* d_ws,
                              size_t ws_size, hipStream_t stream) {
  const int* idx = (const int*)d_in[0];
  const float* emb = (const float*)d_in[1];
  const float* W_V = (const float*)d_in[2];
  const float* W_out = (const float*)d_in[3];
  const float* b_out = (const float*)d_in[4];
  float* out = (float*)d_out;

  if (ws_size < WS_NEED) return;

  char* ws = (char*)d_ws;
  unsigned short* eB = (unsigned short*)(ws + WS_EB);
  unsigned short* wvB = (unsigned short*)(ws + WS_WV);
  unsigned short* woB = (unsigned short*)(ws + WS_WO);
  float* V = (float*)(ws + WS_V);
  unsigned short* avgB = (unsigned short*)(ws + WS_AVG);
  float* part = (float*)(ws + WS_PART);

  // fused weight converts (one launch) + embedding gather
  hipLaunchKernelGGL(cvt_both, dim3(2048), dim3(256), 0, stream, W_V, wvB,
                     (DIMS * DIMS) / 4, W_out, woB, (VOCAB * DIMS) / 4);
  hipLaunchKernelGGL(gather_emb, dim3(ROWS), dim3(256), 0, stream, idx, emb,
                     eB);
  // V = e @ W_V^T  (M=4096, N=1024, K=1024) — old 128^2 kernel, 256 blocks
  hipLaunchKernelGGL(gemm_bt, dim3(ROWS / 128, DIMS / 128), dim3(256), 0,
                     stream, eB, wvB, V, (const float*)nullptr, DIMS, DIMS);
  hipLaunchKernelGGL(chunk_sums, dim3(BATCH * NC), dim3(256), 0, stream, V,
                     part);
  hipLaunchKernelGGL(chunk_scan, dim3((BATCH * DIMS) / 256), dim3(256), 0,
                     stream, part);
  hipLaunchKernelGGL(cum_avg, dim3(BATCH * NC), dim3(256), 0, stream, V, part,
                     avgB);
  // out = avg @ W_out^T + b_out  (M=4096, N=32000, K=1024)
  // grid x = m-tiles (16, fastest): concurrent B working set small,
  // W_out streams once (round-2 counter evidence).
  hipLaunchKernelGGL(gemm256x128_m32, dim3(ROWS / 256, VOCAB / 128), dim3(512),
                     0, stream, avgB, woB, out, b_out, DIMS, VOCAB);
}